// Round 2
// baseline (5141.189 us; speedup 1.0000x reference)
//
#include <hip/hip_runtime.h>
#include <math.h>

// SwinDecoder on MI355X. fp32 baseline, correctness-first, ws-size-adaptive.
// Persistent ws: e (12,582,912 f) + bias_all (393,216 f) = 12,976,128 floats.
// Stage region: reused per chunk; attn chunk of W windows needs W*128*960
// floats (ln 192 + qkv 576 + obuf 192); MLP chunk of R rows needs R*960
// (ln 192 + h 768). Chunk sizes picked at launch from ws_size.

#define CCH 192
#define HEADS 6

__device__ __forceinline__ int zone_z(int z){ return z<30?0:(z<31?1:2); }
__device__ __forceinline__ int zone_hw(int h){ return h<24?0:(h<28?1:2); }

// ---------------- relative position bias gather: bias_all[d][head][n][m] ---
__global__ void bias_precompute(const float* __restrict__ rpb,
                                float* __restrict__ bias_all)
{
    int d = blockIdx.x / HEADS, head = blockIdx.x % HEADS;
    int n = threadIdx.x;
    int i1 = n>>6, j1 = (n>>3)&7, k1 = n&7;
    const float* rp = rpb + d*675*HEADS;
    float* out = bias_all + ((size_t)blockIdx.x*128 + n)*128;
    for (int m = 0; m < 128; ++m){
        int i2 = m>>6, j2 = (m>>3)&7, k2 = m&7;
        int idx = (i1-i2+1)*225 + (j1-j2+7)*15 + (k1-k2+7);
        out[m] = rp[idx*HEADS + head];
    }
}

// ---------------- patch embed + LN: x -> e[pos][192], 4 positions/block ----
__global__ __launch_bounds__(192) void patch_embed_ln(
    const float* __restrict__ x, const float* __restrict__ pe_w,
    const float* __restrict__ pe_b, const float* __restrict__ gg,
    const float* __restrict__ bb, float* __restrict__ e)
{
    __shared__ float xs[4][128];
    __shared__ float red[4][2][3];
    int tid = threadIdx.x;
    int base = blockIdx.x*4;
    for (int idx = tid; idx < 512; idx += 192){
        int p = idx >> 7, t = idx & 127;
        int pos = base + p;
        int w = pos & 31, h = (pos>>5)&31, z = (pos>>10)&31, b = pos>>15;
        int c = t>>5, i = (t>>4)&1, j = (t>>2)&3, k = t&3;
        xs[p][t] = x[ (((size_t)(b*4+c)*64 + (z*2+i))*128 + (h*4+j))*128 + (w*4+k) ];
    }
    __syncthreads();
    float acc[4];
    float b0 = pe_b[tid];
    #pragma unroll
    for (int p=0;p<4;p++) acc[p] = b0;
    const float* wrow = pe_w + tid*128;
    for (int t=0;t<128;t++){
        float wv = wrow[t];
        #pragma unroll
        for (int p=0;p<4;p++) acc[p] += xs[p][t]*wv;
    }
    float s[4], s2[4];
    #pragma unroll
    for (int p=0;p<4;p++){ s[p]=acc[p]; s2[p]=acc[p]*acc[p]; }
    for (int off=32; off>=1; off>>=1){
        #pragma unroll
        for (int p=0;p<4;p++){ s[p]+=__shfl_xor(s[p],off); s2[p]+=__shfl_xor(s2[p],off); }
    }
    int wvid = tid>>6;
    if ((tid&63)==0){
        #pragma unroll
        for (int p=0;p<4;p++){ red[p][0][wvid]=s[p]; red[p][1][wvid]=s2[p]; }
    }
    __syncthreads();
    float gv = gg[tid], bv = bb[tid];
    #pragma unroll
    for (int p=0;p<4;p++){
        float sum = red[p][0][0]+red[p][0][1]+red[p][0][2];
        float sq  = red[p][1][0]+red[p][1][1]+red[p][1][2];
        float mean = sum*(1.f/192.f);
        float var = sq*(1.f/192.f) - mean*mean;
        float rstd = rsqrtf(var + 1e-5f);
        e[(size_t)(base+p)*CCH + tid] = (acc[p]-mean)*rstd*gv + bv;
    }
}

// ---------------- LayerNorm; window_mode gathers shifted window rows -------
// Reads e at GLOBAL row (blockIdx.x + row0); writes outp at LOCAL row.
__global__ __launch_bounds__(192) void ln_kernel(
    const float* __restrict__ in, float* __restrict__ outp,
    const float* __restrict__ gg, const float* __restrict__ bb,
    int window_mode, int shifted, int row0)
{
    int tid = threadIdx.x;
    int r = blockIdx.x + row0;
    int src;
    if (window_mode){
        int wb = r>>7, tok = r&127;
        int b = wb>>8, nw = wb&255;
        int zs = (nw>>4)*2 + (tok>>6);
        int hs = ((nw>>2)&3)*8 + ((tok>>3)&7);
        int ws = (nw&3)*8 + (tok&7);
        int z,h,w;
        if (shifted){ z=(zs+1)&31; h=(hs+4)&31; w=(ws+4)&31; }
        else        { z=zs; h=hs; w=ws; }
        src = ((b*32+z)*32+h)*32+w;
    } else src = r;
    float val = in[(size_t)src*CCH + tid];
    float s = val, s2 = val*val;
    for (int off=32; off>=1; off>>=1){ s += __shfl_xor(s,off); s2 += __shfl_xor(s2,off); }
    __shared__ float red[2][3];
    if ((tid&63)==0){ red[0][tid>>6]=s; red[1][tid>>6]=s2; }
    __syncthreads();
    float sum = red[0][0]+red[0][1]+red[0][2];
    float sq  = red[1][0]+red[1][1]+red[1][2];
    float mean = sum*(1.f/192.f);
    float rstd = rsqrtf(sq*(1.f/192.f) - mean*mean + 1e-5f);
    outp[(size_t)blockIdx.x*CCH + tid] = (val-mean)*rstd*gg[tid] + bb[tid];
}

// ---------------- tiled fp32 GEMM, 64x64 tile, 4x4 per thread -------------
// A is LOCAL (chunk) rows. MODE 0: C=A*B+bias (local). 1: gelu (local).
// MODE 2: window-reverse+unshift+residual scatter-add into e at GLOBAL rows.
// MODE 3: C(global rows) += A*B+bias.
template<int MODE>
__global__ __launch_bounds__(256) void gemm_kernel(
    const float* __restrict__ A, const float* __restrict__ B,
    const float* __restrict__ bias, float* __restrict__ Cout,
    int N, int K, int shifted, int row0)
{
    __shared__ float As[16][64];
    __shared__ float Bs[16][64];
    int t = threadIdx.x;
    int tx = t & 15, ty = t >> 4;
    int m0 = blockIdx.y*64, n0 = blockIdx.x*64;
    float acc[4][4];
    #pragma unroll
    for (int i=0;i<4;i++)
        #pragma unroll
        for (int j=0;j<4;j++) acc[i][j]=0.f;
    int am = t >> 2, akq = t & 3;
    int bk = t >> 4, bnq = t & 15;
    for (int k0 = 0; k0 < K; k0 += 16){
        float4 a4 = *(const float4*)&A[(size_t)(m0+am)*K + k0 + akq*4];
        float4 b4 = *(const float4*)&B[(size_t)(k0+bk)*N + n0 + bnq*4];
        As[akq*4+0][am]=a4.x; As[akq*4+1][am]=a4.y;
        As[akq*4+2][am]=a4.z; As[akq*4+3][am]=a4.w;
        *(float4*)&Bs[bk][bnq*4] = b4;
        __syncthreads();
        #pragma unroll
        for (int kk=0;kk<16;kk++){
            float4 av = *(const float4*)&As[kk][ty*4];
            float4 bv = *(const float4*)&Bs[kk][tx*4];
            acc[0][0]+=av.x*bv.x; acc[0][1]+=av.x*bv.y; acc[0][2]+=av.x*bv.z; acc[0][3]+=av.x*bv.w;
            acc[1][0]+=av.y*bv.x; acc[1][1]+=av.y*bv.y; acc[1][2]+=av.y*bv.z; acc[1][3]+=av.y*bv.w;
            acc[2][0]+=av.z*bv.x; acc[2][1]+=av.z*bv.y; acc[2][2]+=av.z*bv.z; acc[2][3]+=av.z*bv.w;
            acc[3][0]+=av.w*bv.x; acc[3][1]+=av.w*bv.y; acc[3][2]+=av.w*bv.z; acc[3][3]+=av.w*bv.w;
        }
        __syncthreads();
    }
    #pragma unroll
    for (int i=0;i<4;i++){
        int m = m0 + ty*4 + i;
        #pragma unroll
        for (int j=0;j<4;j++){
            int n = n0 + tx*4 + j;
            float v = acc[i][j] + bias[n];
            if (MODE==1) v = 0.5f*v*(1.f + erff(v*0.70710678118654752f));
            if (MODE==0 || MODE==1){
                Cout[(size_t)m*N + n] = v;
            } else if (MODE==3){
                Cout[(size_t)(m+row0)*N + n] += v;
            } else { // MODE 2
                int mg = m + row0;
                int wb = mg>>7, tok = mg&127;
                int b = wb>>8, nw = wb&255;
                int zs = (nw>>4)*2 + (tok>>6);
                int hs = ((nw>>2)&3)*8 + ((tok>>3)&7);
                int ws = (nw&3)*8 + (tok&7);
                int z,h,w;
                if (shifted){ z=(zs+1)&31; h=(hs+4)&31; w=(ws+4)&31; }
                else        { z=zs; h=hs; w=ws; }
                Cout[(size_t)(((b*32+z)*32+h)*32+w)*CCH + n] += v;
            }
        }
    }
}

// ---------------- attention: one (window, head) per block ------------------
// qkv/obuf indexed by LOCAL window; group labels use GLOBAL window (wb0+).
__global__ __launch_bounds__(128) void attn_kernel(
    const float* __restrict__ qkv, float* __restrict__ obuf,
    const float* __restrict__ bias_layer, int shifted, int wb0)
{
    __shared__ float ks[128*32];
    __shared__ float vs[128*32];
    __shared__ int grp[128];
    int tid = threadIdx.x;
    int wb = blockIdx.x / HEADS;          // local window
    int head = blockIdx.x % HEADS;
    int nw = (wb + wb0) & 255;            // global window within batch image
    #pragma unroll
    for (int i=0;i<8;i++){
        int idx = i*128 + tid;
        int row = idx>>3, dq = idx&7;
        const float4* src = (const float4*)(qkv + (size_t)(wb*128+row)*576 + head*32) + dq;
        *(float4*)&ks[row*32+dq*4] = src[48];   // +192 floats -> K
        *(float4*)&vs[row*32+dq*4] = src[96];   // +384 floats -> V
    }
    float q[32];
    {
        const float4* qsrc = (const float4*)(qkv + (size_t)(wb*128+tid)*576 + head*32);
        const float scale = 0.17677669529663689f; // 32^-0.5
        #pragma unroll
        for (int i=0;i<8;i++){
            float4 v4 = qsrc[i];
            q[i*4+0]=v4.x*scale; q[i*4+1]=v4.y*scale;
            q[i*4+2]=v4.z*scale; q[i*4+3]=v4.w*scale;
        }
    }
    if (shifted){
        int zs = (nw>>4)*2 + (tid>>6);
        int hs = ((nw>>2)&3)*8 + ((tid>>3)&7);
        int ws = (nw&3)*8 + (tid&7);
        grp[tid] = zone_z(zs)*9 + zone_hw(hs)*3 + zone_hw(ws);
    }
    __syncthreads();
    const float* brow = bias_layer + (size_t)(head*128 + tid)*128;
    float mrun = -1e30f, l = 0.f;
    float o[32];
    #pragma unroll
    for (int d=0;d<32;d++) o[d]=0.f;
    int myg = shifted ? grp[tid] : 0;
    for (int m=0;m<128;m++){
        float s = 0.f;
        #pragma unroll
        for (int dq=0;dq<8;dq++){
            float4 k4 = *(const float4*)&ks[m*32+dq*4];
            s += q[dq*4+0]*k4.x + q[dq*4+1]*k4.y + q[dq*4+2]*k4.z + q[dq*4+3]*k4.w;
        }
        s += brow[m];
        if (shifted && grp[m]!=myg) s -= 100.f;
        float mnew = fmaxf(mrun, s);
        float alpha = __expf(mrun - mnew);
        float p = __expf(s - mnew);
        l = l*alpha + p;
        #pragma unroll
        for (int dq=0;dq<8;dq++){
            float4 v4 = *(const float4*)&vs[m*32+dq*4];
            o[dq*4+0] = o[dq*4+0]*alpha + p*v4.x;
            o[dq*4+1] = o[dq*4+1]*alpha + p*v4.y;
            o[dq*4+2] = o[dq*4+2]*alpha + p*v4.z;
            o[dq*4+3] = o[dq*4+3]*alpha + p*v4.w;
        }
        mrun = mnew;
    }
    float inv = 1.f/l;
    float* dst = obuf + (size_t)(wb*128+tid)*CCH + head*32;
    #pragma unroll
    for (int i=0;i<8;i++){
        float4 v4 = make_float4(o[i*4+0]*inv, o[i*4+1]*inv, o[i*4+2]*inv, o[i*4+3]*inv);
        *(float4*)&dst[i*4] = v4;
    }
}

// ---------------- reconstruction: e -> out, 8 positions/block --------------
__global__ __launch_bounds__(128) void recon_kernel(
    const float* __restrict__ e, const float* __restrict__ rec_w,
    const float* __restrict__ rec_b, float* __restrict__ out)
{
    __shared__ float es[8*192];
    int tid = threadIdx.x;
    int base = blockIdx.x*8;
    for (int idx = tid; idx < 8*192; idx += 128)
        es[idx] = e[(size_t)base*CCH + idx];
    __syncthreads();
    int o = tid>>5, i = (tid>>4)&1, j = (tid>>2)&3, k = tid&3;
    float acc[8];
    float rb = rec_b[o];
    #pragma unroll
    for (int p=0;p<8;p++) acc[p]=rb;
    for (int c=0;c<192;c++){
        float wv = rec_w[c*128 + tid];
        #pragma unroll
        for (int p=0;p<8;p++) acc[p] += es[p*192+c]*wv;
    }
    #pragma unroll
    for (int p=0;p<8;p++){
        int pos = base + p;
        int w = pos&31, h=(pos>>5)&31, z=(pos>>10)&31, b=pos>>15;
        out[ (((size_t)(b*4+o)*64 + (z*2+i))*128 + (h*4+j))*128 + (w*4+k) ] = acc[p];
    }
}

extern "C" void kernel_launch(void* const* d_in, const int* in_sizes, int n_in,
                              void* d_out, int out_size, void* d_ws, size_t ws_size,
                              hipStream_t stream) {
    const float* x       = (const float*)d_in[0];
    const float* pe_w    = (const float*)d_in[1];
    const float* pe_b    = (const float*)d_in[2];
    const float* pe_ln_g = (const float*)d_in[3];
    const float* pe_ln_b = (const float*)d_in[4];
    const float* ln1_g   = (const float*)d_in[5];
    const float* ln1_b   = (const float*)d_in[6];
    const float* qkv_w   = (const float*)d_in[7];
    const float* qkv_b   = (const float*)d_in[8];
    const float* proj_w  = (const float*)d_in[9];
    const float* proj_b  = (const float*)d_in[10];
    const float* rpb     = (const float*)d_in[11];
    const float* ln2_g   = (const float*)d_in[12];
    const float* ln2_b   = (const float*)d_in[13];
    const float* fc1_w   = (const float*)d_in[14];
    const float* fc1_b   = (const float*)d_in[15];
    const float* fc2_w   = (const float*)d_in[16];
    const float* fc2_b   = (const float*)d_in[17];
    const float* rec_w   = (const float*)d_in[18];
    const float* rec_b   = (const float*)d_in[19];
    float* out = (float*)d_out;
    float* ws  = (float*)d_ws;

    float* e        = ws;                          // 12,582,912 floats
    float* bias_all = ws + 12582912;               //    393,216 floats
    float* stage    = ws + 12976128;
    size_t cap      = ws_size / sizeof(float);
    size_t scap     = cap > 12976128 ? cap - 12976128 : 0;

    // attention chunk: W windows -> W*128*960 floats of stage
    int WCH = 512;
    while (WCH > 16 && (size_t)WCH*128*960 > scap) WCH >>= 1;
    // MLP chunk: R rows -> R*960 floats of stage
    int RCH = 65536;
    while (RCH > 2048 && (size_t)RCH*960 > scap) RCH >>= 1;

    bias_precompute<<<24, 128, 0, stream>>>(rpb, bias_all);
    patch_embed_ln<<<16384, 192, 0, stream>>>(x, pe_w, pe_b, pe_ln_g, pe_ln_b, e);

    for (int d = 0; d < 4; ++d){
        int sh = d & 1;
        for (int w0 = 0; w0 < 512; w0 += WCH){
            int rows = WCH*128;
            float* bufc = stage;
            float* qkvc = stage + (size_t)rows*192;
            float* oc   = qkvc + (size_t)rows*576;
            ln_kernel<<<rows, 192, 0, stream>>>(
                e, bufc, ln1_g + d*CCH, ln1_b + d*CCH, 1, sh, w0*128);
            gemm_kernel<0><<<dim3(9, rows/64), 256, 0, stream>>>(
                bufc, qkv_w + d*CCH*3*CCH, qkv_b + d*3*CCH, qkvc, 576, 192, 0, 0);
            attn_kernel<<<WCH*HEADS, 128, 0, stream>>>(
                qkvc, oc, bias_all + (size_t)d*HEADS*128*128, sh, w0);
            gemm_kernel<2><<<dim3(3, rows/64), 256, 0, stream>>>(
                oc, proj_w + d*CCH*CCH, proj_b + d*CCH, e, 192, 192, sh, w0*128);
        }
        for (int r0 = 0; r0 < 65536; r0 += RCH){
            float* lnc = stage;
            float* hc  = stage + (size_t)RCH*192;
            ln_kernel<<<RCH, 192, 0, stream>>>(
                e, lnc, ln2_g + d*CCH, ln2_b + d*CCH, 0, 0, r0);
            gemm_kernel<1><<<dim3(12, RCH/64), 256, 0, stream>>>(
                lnc, fc1_w + d*CCH*4*CCH, fc1_b + d*4*CCH, hc, 768, 192, 0, 0);
            gemm_kernel<3><<<dim3(3, RCH/64), 256, 0, stream>>>(
                hc, fc2_w + d*4*CCH*CCH, fc2_b + d*CCH, e, 192, 768, 0, r0);
        }
    }
    recon_kernel<<<8192, 128, 0, stream>>>(e, rec_w, rec_b, out);
}

// Round 3
// 2472.653 us; speedup vs baseline: 2.0792x; 2.0792x over previous
//
#include <hip/hip_runtime.h>
#include <math.h>

// SwinDecoder on MI355X. Round 3: bf16 MFMA GEMMs (qkv/proj/fc1/fc2).
// Residual stream e stays fp32; weights converted+transposed to bf16 once
// per call; LN / gelu / attn outputs emitted as bf16 (GEMM A operands).
// ws layout (bytes):
//   e        : 0          .. 50,331,648   fp32 [65536][192]
//   bias_all : 50,331,648 .. 51,904,512   fp32 [4][6][128][128]
//   wt       : 51,904,512 .. 55,443,456   bf16 transposed weights
//   stage    : 55,443,456 .. (chunked)

#define CCH 192
#define HEADS 6

typedef __attribute__((ext_vector_type(8))) short bf16x8;
typedef __attribute__((ext_vector_type(4))) float f32x4;

__device__ __forceinline__ unsigned short f2bf(float f){
    union { float f; unsigned int u; } x; x.f = f;
    unsigned int r = (x.u + 0x7fffu + ((x.u >> 16) & 1u)) >> 16;
    return (unsigned short)r;
}

__device__ __forceinline__ void async16(const void* g, void* l){
    __builtin_amdgcn_global_load_lds(
        (const __attribute__((address_space(1))) void*)g,
        (__attribute__((address_space(3))) void*)l, 16, 0, 0);
}

__device__ __forceinline__ int zone_z(int z){ return z<30?0:(z<31?1:2); }
__device__ __forceinline__ int zone_hw(int h){ return h<24?0:(h<28?1:2); }

// ---------------- weight convert+transpose: w[K][N] fp32 -> wt[N][K] bf16 --
__global__ void wt_convert(const float* __restrict__ w, unsigned short* __restrict__ wt,
                           int K, int N)
{
    int idx = blockIdx.x*256 + threadIdx.x;
    if (idx >= K*N) return;
    int n = idx / K, k = idx - n*K;
    wt[idx] = f2bf(w[(size_t)k*N + n]);
}

// ---------------- relative position bias gather: bias_all[d][head][n][m] ---
__global__ void bias_precompute(const float* __restrict__ rpb,
                                float* __restrict__ bias_all)
{
    int d = blockIdx.x / HEADS, head = blockIdx.x % HEADS;
    int n = threadIdx.x;
    int i1 = n>>6, j1 = (n>>3)&7, k1 = n&7;
    const float* rp = rpb + d*675*HEADS;
    float* out = bias_all + ((size_t)blockIdx.x*128 + n)*128;
    for (int m = 0; m < 128; ++m){
        int i2 = m>>6, j2 = (m>>3)&7, k2 = m&7;
        int idx = (i1-i2+1)*225 + (j1-j2+7)*15 + (k1-k2+7);
        out[m] = rp[idx*HEADS + head];
    }
}

// ---------------- patch embed + LN: x -> e[pos][192], 4 positions/block ----
__global__ __launch_bounds__(192) void patch_embed_ln(
    const float* __restrict__ x, const float* __restrict__ pe_w,
    const float* __restrict__ pe_b, const float* __restrict__ gg,
    const float* __restrict__ bb, float* __restrict__ e)
{
    __shared__ float xs[4][128];
    __shared__ float red[4][2][3];
    int tid = threadIdx.x;
    int base = blockIdx.x*4;
    for (int idx = tid; idx < 512; idx += 192){
        int p = idx >> 7, t = idx & 127;
        int pos = base + p;
        int w = pos & 31, h = (pos>>5)&31, z = (pos>>10)&31, b = pos>>15;
        int c = t>>5, i = (t>>4)&1, j = (t>>2)&3, k = t&3;
        xs[p][t] = x[ (((size_t)(b*4+c)*64 + (z*2+i))*128 + (h*4+j))*128 + (w*4+k) ];
    }
    __syncthreads();
    float acc[4];
    float b0 = pe_b[tid];
    #pragma unroll
    for (int p=0;p<4;p++) acc[p] = b0;
    const float* wrow = pe_w + tid*128;
    for (int t=0;t<128;t+=4){
        float4 w4 = *(const float4*)&wrow[t];
        #pragma unroll
        for (int p=0;p<4;p++){
            acc[p] += xs[p][t]*w4.x + xs[p][t+1]*w4.y + xs[p][t+2]*w4.z + xs[p][t+3]*w4.w;
        }
    }
    float s[4], s2[4];
    #pragma unroll
    for (int p=0;p<4;p++){ s[p]=acc[p]; s2[p]=acc[p]*acc[p]; }
    for (int off=32; off>=1; off>>=1){
        #pragma unroll
        for (int p=0;p<4;p++){ s[p]+=__shfl_xor(s[p],off); s2[p]+=__shfl_xor(s2[p],off); }
    }
    int wvid = tid>>6;
    if ((tid&63)==0){
        #pragma unroll
        for (int p=0;p<4;p++){ red[p][0][wvid]=s[p]; red[p][1][wvid]=s2[p]; }
    }
    __syncthreads();
    float gv = gg[tid], bv = bb[tid];
    #pragma unroll
    for (int p=0;p<4;p++){
        float sum = red[p][0][0]+red[p][0][1]+red[p][0][2];
        float sq  = red[p][1][0]+red[p][1][1]+red[p][1][2];
        float mean = sum*(1.f/192.f);
        float var = sq*(1.f/192.f) - mean*mean;
        float rstd = rsqrtf(var + 1e-5f);
        e[(size_t)(base+p)*CCH + tid] = (acc[p]-mean)*rstd*gv + bv;
    }
}

// ---------------- LayerNorm -> bf16; window_mode gathers shifted rows ------
// Reads e at GLOBAL row (blockIdx.x + row0); writes outp at LOCAL row.
__global__ __launch_bounds__(192) void ln_kernel(
    const float* __restrict__ in, unsigned short* __restrict__ outp,
    const float* __restrict__ gg, const float* __restrict__ bb,
    int window_mode, int shifted, int row0)
{
    int tid = threadIdx.x;
    int r = blockIdx.x + row0;
    int src;
    if (window_mode){
        int wb = r>>7, tok = r&127;
        int b = wb>>8, nw = wb&255;
        int zs = (nw>>4)*2 + (tok>>6);
        int hs = ((nw>>2)&3)*8 + ((tok>>3)&7);
        int ws = (nw&3)*8 + (tok&7);
        int z,h,w;
        if (shifted){ z=(zs+1)&31; h=(hs+4)&31; w=(ws+4)&31; }
        else        { z=zs; h=hs; w=ws; }
        src = ((b*32+z)*32+h)*32+w;
    } else src = r;
    float val = in[(size_t)src*CCH + tid];
    float s = val, s2 = val*val;
    for (int off=32; off>=1; off>>=1){ s += __shfl_xor(s,off); s2 += __shfl_xor(s2,off); }
    __shared__ float red[2][3];
    if ((tid&63)==0){ red[0][tid>>6]=s; red[1][tid>>6]=s2; }
    __syncthreads();
    float sum = red[0][0]+red[0][1]+red[0][2];
    float sq  = red[1][0]+red[1][1]+red[1][2];
    float mean = sum*(1.f/192.f);
    float rstd = rsqrtf(sq*(1.f/192.f) - mean*mean + 1e-5f);
    outp[(size_t)blockIdx.x*CCH + tid] = f2bf((val-mean)*rstd*gg[tid] + bb[tid]);
}

// ---------------- bf16 MFMA GEMM: C = A * Bt^T + bias ----------------------
// A [rows][K] bf16 (local rows), Bt [N][K] bf16. 128x64 tile, BK=32,
// 256 thr = 4 waves; wave w: rows [w*32, w*32+32), all 64 cols.
// MODE 0: fp32 out (local). 1: gelu -> bf16 out (local).
// MODE 2: window-reverse+unshift residual add into e fp32 (global rows).
// MODE 3: fp32 Cout(global rows) += .
template<int MODE>
__global__ __launch_bounds__(256) void gemm_mfma(
    const unsigned short* __restrict__ A, const unsigned short* __restrict__ Bt,
    const float* __restrict__ bias, void* __restrict__ Cout,
    int N, int K, int shifted, int row0)
{
    __shared__ unsigned short As[128*32];
    __shared__ unsigned short Bs[64*32];
    int t = threadIdx.x;
    int wave = t >> 6, lane = t & 63;
    int quad = lane >> 4, l16 = lane & 15;
    int m0 = blockIdx.y * 128, n0 = blockIdx.x * 64;

    f32x4 acc[2][4] = {};
    int ldrow = lane >> 2;       // 0..15
    int ldk   = (lane & 3) * 8;  // 0,8,16,24

    for (int k0 = 0; k0 < K; k0 += 32){
        #pragma unroll
        for (int s2 = 0; s2 < 2; ++s2){
            int s = wave*2 + s2;
            async16(A + (size_t)(m0 + s*16 + ldrow)*K + k0 + ldk, &As[s*512]);
        }
        async16(Bt + (size_t)(n0 + wave*16 + ldrow)*K + k0 + ldk, &Bs[wave*512]);
        __syncthreads();
        bf16x8 af[2], bfr[4];
        #pragma unroll
        for (int mt=0; mt<2; ++mt)
            af[mt] = *(const bf16x8*)&As[(wave*32 + mt*16 + l16)*32 + quad*8];
        #pragma unroll
        for (int nt=0; nt<4; ++nt)
            bfr[nt] = *(const bf16x8*)&Bs[(nt*16 + l16)*32 + quad*8];
        #pragma unroll
        for (int mt=0; mt<2; ++mt)
            #pragma unroll
            for (int nt=0; nt<4; ++nt)
                acc[mt][nt] = __builtin_amdgcn_mfma_f32_16x16x32_bf16(
                    af[mt], bfr[nt], acc[mt][nt], 0, 0, 0);
        __syncthreads();
    }

    float* Cf = (float*)Cout;
    unsigned short* Ch = (unsigned short*)Cout;
    #pragma unroll
    for (int mt=0; mt<2; ++mt){
        #pragma unroll
        for (int nt=0; nt<4; ++nt){
            #pragma unroll
            for (int r=0; r<4; ++r){
                int m = m0 + wave*32 + mt*16 + quad*4 + r;
                int n = n0 + nt*16 + l16;
                float v = acc[mt][nt][r] + bias[n];
                if (MODE==0){
                    Cf[(size_t)m*N + n] = v;
                } else if (MODE==1){
                    v = 0.5f*v*(1.f + erff(v*0.70710678118654752f));
                    Ch[(size_t)m*N + n] = f2bf(v);
                } else if (MODE==3){
                    Cf[(size_t)(m+row0)*N + n] += v;
                } else {
                    int mg = m + row0;
                    int wb = mg>>7, tok = mg&127;
                    int b = wb>>8, nw = wb&255;
                    int zs = (nw>>4)*2 + (tok>>6);
                    int hs = ((nw>>2)&3)*8 + ((tok>>3)&7);
                    int ws = (nw&3)*8 + (tok&7);
                    int z,h,w;
                    if (shifted){ z=(zs+1)&31; h=(hs+4)&31; w=(ws+4)&31; }
                    else        { z=zs; h=hs; w=ws; }
                    Cf[(size_t)(((b*32+z)*32+h)*32+w)*CCH + n] += v;
                }
            }
        }
    }
}

// ---------------- attention: one (window, head) per block ------------------
// qkv fp32 (local windows); obuf bf16. Group labels use GLOBAL window.
__global__ __launch_bounds__(128) void attn_kernel(
    const float* __restrict__ qkv, unsigned short* __restrict__ obuf,
    const float* __restrict__ bias_layer, int shifted, int wb0)
{
    __shared__ float ks[128*32];
    __shared__ float vs[128*32];
    __shared__ int grp[128];
    int tid = threadIdx.x;
    int wb = blockIdx.x / HEADS;
    int head = blockIdx.x % HEADS;
    int nw = (wb + wb0) & 255;
    #pragma unroll
    for (int i=0;i<8;i++){
        int idx = i*128 + tid;
        int row = idx>>3, dq = idx&7;
        const float4* src = (const float4*)(qkv + (size_t)(wb*128+row)*576 + head*32) + dq;
        *(float4*)&ks[row*32+dq*4] = src[48];
        *(float4*)&vs[row*32+dq*4] = src[96];
    }
    float q[32];
    {
        const float4* qsrc = (const float4*)(qkv + (size_t)(wb*128+tid)*576 + head*32);
        const float scale = 0.17677669529663689f;
        #pragma unroll
        for (int i=0;i<8;i++){
            float4 v4 = qsrc[i];
            q[i*4+0]=v4.x*scale; q[i*4+1]=v4.y*scale;
            q[i*4+2]=v4.z*scale; q[i*4+3]=v4.w*scale;
        }
    }
    if (shifted){
        int zs = (nw>>4)*2 + (tid>>6);
        int hs = ((nw>>2)&3)*8 + ((tid>>3)&7);
        int ws = (nw&3)*8 + (tid&7);
        grp[tid] = zone_z(zs)*9 + zone_hw(hs)*3 + zone_hw(ws);
    }
    __syncthreads();
    const float* brow = bias_layer + (size_t)(head*128 + tid)*128;
    float mrun = -1e30f, l = 0.f;
    float o[32];
    #pragma unroll
    for (int d=0;d<32;d++) o[d]=0.f;
    int myg = shifted ? grp[tid] : 0;
    for (int m=0;m<128;m++){
        float s = 0.f;
        #pragma unroll
        for (int dq=0;dq<8;dq++){
            float4 k4 = *(const float4*)&ks[m*32+dq*4];
            s += q[dq*4+0]*k4.x + q[dq*4+1]*k4.y + q[dq*4+2]*k4.z + q[dq*4+3]*k4.w;
        }
        s += brow[m];
        if (shifted && grp[m]!=myg) s -= 100.f;
        float mnew = fmaxf(mrun, s);
        float alpha = __expf(mrun - mnew);
        float p = __expf(s - mnew);
        l = l*alpha + p;
        #pragma unroll
        for (int dq=0;dq<8;dq++){
            float4 v4 = *(const float4*)&vs[m*32+dq*4];
            o[dq*4+0] = o[dq*4+0]*alpha + p*v4.x;
            o[dq*4+1] = o[dq*4+1]*alpha + p*v4.y;
            o[dq*4+2] = o[dq*4+2]*alpha + p*v4.z;
            o[dq*4+3] = o[dq*4+3]*alpha + p*v4.w;
        }
        mrun = mnew;
    }
    float inv = 1.f/l;
    unsigned short* dst = obuf + (size_t)(wb*128+tid)*CCH + head*32;
    #pragma unroll
    for (int i=0;i<8;i++){
        ushort4 v4;
        v4.x = f2bf(o[i*4+0]*inv); v4.y = f2bf(o[i*4+1]*inv);
        v4.z = f2bf(o[i*4+2]*inv); v4.w = f2bf(o[i*4+3]*inv);
        *(ushort4*)&dst[i*4] = v4;
    }
}

// ---------------- reconstruction: e -> out, 8 positions/block --------------
__global__ __launch_bounds__(128) void recon_kernel(
    const float* __restrict__ e, const float* __restrict__ rec_w,
    const float* __restrict__ rec_b, float* __restrict__ out)
{
    __shared__ float es[8*192];
    int tid = threadIdx.x;
    int base = blockIdx.x*8;
    for (int idx = tid; idx < 8*192; idx += 128)
        es[idx] = e[(size_t)base*CCH + idx];
    __syncthreads();
    int o = tid>>5, i = (tid>>4)&1, j = (tid>>2)&3, k = tid&3;
    float acc[8];
    float rb = rec_b[o];
    #pragma unroll
    for (int p=0;p<8;p++) acc[p]=rb;
    for (int c=0;c<192;c++){
        float wv = rec_w[c*128 + tid];
        #pragma unroll
        for (int p=0;p<8;p++) acc[p] += es[p*192+c]*wv;
    }
    #pragma unroll
    for (int p=0;p<8;p++){
        int pos = base + p;
        int w = pos&31, h=(pos>>5)&31, z=(pos>>10)&31, b=pos>>15;
        out[ (((size_t)(b*4+o)*64 + (z*2+i))*128 + (h*4+j))*128 + (w*4+k) ] = acc[p];
    }
}

extern "C" void kernel_launch(void* const* d_in, const int* in_sizes, int n_in,
                              void* d_out, int out_size, void* d_ws, size_t ws_size,
                              hipStream_t stream) {
    const float* x       = (const float*)d_in[0];
    const float* pe_w    = (const float*)d_in[1];
    const float* pe_b    = (const float*)d_in[2];
    const float* pe_ln_g = (const float*)d_in[3];
    const float* pe_ln_b = (const float*)d_in[4];
    const float* ln1_g   = (const float*)d_in[5];
    const float* ln1_b   = (const float*)d_in[6];
    const float* qkv_w   = (const float*)d_in[7];
    const float* qkv_b   = (const float*)d_in[8];
    const float* proj_w  = (const float*)d_in[9];
    const float* proj_b  = (const float*)d_in[10];
    const float* rpb     = (const float*)d_in[11];
    const float* ln2_g   = (const float*)d_in[12];
    const float* ln2_b   = (const float*)d_in[13];
    const float* fc1_w   = (const float*)d_in[14];
    const float* fc1_b   = (const float*)d_in[15];
    const float* fc2_w   = (const float*)d_in[16];
    const float* fc2_b   = (const float*)d_in[17];
    const float* rec_w   = (const float*)d_in[18];
    const float* rec_b   = (const float*)d_in[19];
    float* out = (float*)d_out;
    char* wsb = (char*)d_ws;

    float*          e        = (float*)wsb;                    // 50,331,648 B
    float*          bias_all = (float*)(wsb + 50331648);       //  1,572,864 B
    unsigned short* wt       = (unsigned short*)(wsb + 51904512); // 3,538,944 B
    char*           stage    = wsb + 55443456;
    size_t scap = ws_size > 55443456 ? ws_size - 55443456 : 0;

    // attention chunk: W windows -> W*128 rows, 3072 B/row of stage
    int WCH = 512;
    while (WCH > 16 && (size_t)WCH*128*3072 > scap) WCH >>= 1;
    // MLP chunk: R rows, 1920 B/row
    int RCH = 65536;
    while (RCH > 2048 && (size_t)RCH*1920 > scap) RCH >>= 1;

    // transposed bf16 weights, per layer: qkv(0) proj(110592) fc1(147456) fc2(294912)
    for (int d = 0; d < 4; ++d){
        unsigned short* wl = wt + (size_t)d*442368;
        wt_convert<<<(110592+255)/256, 256, 0, stream>>>(qkv_w  + (size_t)d*110592, wl,          192, 576);
        wt_convert<<<( 36864+255)/256, 256, 0, stream>>>(proj_w + (size_t)d* 36864, wl + 110592, 192, 192);
        wt_convert<<<(147456+255)/256, 256, 0, stream>>>(fc1_w  + (size_t)d*147456, wl + 147456, 192, 768);
        wt_convert<<<(147456+255)/256, 256, 0, stream>>>(fc2_w  + (size_t)d*147456, wl + 294912, 768, 192);
    }

    bias_precompute<<<24, 128, 0, stream>>>(rpb, bias_all);
    patch_embed_ln<<<16384, 192, 0, stream>>>(x, pe_w, pe_b, pe_ln_g, pe_ln_b, e);

    for (int d = 0; d < 4; ++d){
        int sh = d & 1;
        unsigned short* wl = wt + (size_t)d*442368;
        for (int w0 = 0; w0 < 512; w0 += WCH){
            int rows = WCH*128;
            unsigned short* bufc = (unsigned short*)stage;
            float*          qkvc = (float*)(stage + (size_t)rows*384);
            unsigned short* oc   = (unsigned short*)(stage + (size_t)rows*(384+2304));
            ln_kernel<<<rows, 192, 0, stream>>>(
                e, bufc, ln1_g + d*CCH, ln1_b + d*CCH, 1, sh, w0*128);
            gemm_mfma<0><<<dim3(9, rows/128), 256, 0, stream>>>(
                bufc, wl, qkv_b + d*3*CCH, qkvc, 576, 192, 0, 0);
            attn_kernel<<<WCH*HEADS, 128, 0, stream>>>(
                qkvc, oc, bias_all + (size_t)d*HEADS*128*128, sh, w0);
            gemm_mfma<2><<<dim3(3, rows/128), 256, 0, stream>>>(
                oc, wl + 110592, proj_b + d*CCH, e, 192, 192, sh, w0*128);
        }
        for (int r0 = 0; r0 < 65536; r0 += RCH){
            unsigned short* lnc = (unsigned short*)stage;
            unsigned short* hc  = (unsigned short*)(stage + (size_t)RCH*384);
            ln_kernel<<<RCH, 192, 0, stream>>>(
                e, lnc, ln2_g + d*CCH, ln2_b + d*CCH, 0, 0, r0);
            gemm_mfma<1><<<dim3(12, RCH/128), 256, 0, stream>>>(
                lnc, wl + 147456, fc1_b + d*4*CCH, hc, 768, 192, 0, 0);
            gemm_mfma<3><<<dim3(3, RCH/128), 256, 0, stream>>>(
                hc, wl + 294912, fc2_b + d*CCH, e, 192, 768, 0, r0);
        }
    }
    recon_kernel<<<8192, 128, 0, stream>>>(e, rec_w, rec_b, out);
}

// Round 4
// 2028.720 us; speedup vs baseline: 2.5342x; 1.2188x over previous
//
#include <hip/hip_runtime.h>
#include <math.h>

// SwinDecoder on MI355X. Round 4: MFMA attention + vectorized patch-embed.
// ws layout (bytes):
//   e        : 0          .. 50,331,648   fp32 [65536][192]
//   bias_all : 50,331,648 .. 51,904,512   fp32 [4][6][128][128]
//   wt       : 51,904,512 .. 55,443,456   bf16 transposed weights
//   stage    : 55,443,456 .. (chunked)

#define CCH 192
#define HEADS 6

typedef __attribute__((ext_vector_type(8))) short bf16x8;
typedef __attribute__((ext_vector_type(4))) float f32x4;

__device__ __forceinline__ unsigned short f2bf(float f){
    union { float f; unsigned int u; } x; x.f = f;
    unsigned int r = (x.u + 0x7fffu + ((x.u >> 16) & 1u)) >> 16;
    return (unsigned short)r;
}

__device__ __forceinline__ void async16(const void* g, void* l){
    __builtin_amdgcn_global_load_lds(
        (const __attribute__((address_space(1))) void*)g,
        (__attribute__((address_space(3))) void*)l, 16, 0, 0);
}

// load bf16x8 from LDS as two 8B reads (stride need only be 8B-aligned)
__device__ __forceinline__ bf16x8 ld_bf8(const unsigned short* p){
    ushort4 lo = *(const ushort4*)p;
    ushort4 hi = *(const ushort4*)(p+4);
    bf16x8 r;
    r[0]=(short)lo.x; r[1]=(short)lo.y; r[2]=(short)lo.z; r[3]=(short)lo.w;
    r[4]=(short)hi.x; r[5]=(short)hi.y; r[6]=(short)hi.z; r[7]=(short)hi.w;
    return r;
}

__device__ __forceinline__ ushort4 cvt4(float4 v){
    ushort4 r; r.x=f2bf(v.x); r.y=f2bf(v.y); r.z=f2bf(v.z); r.w=f2bf(v.w);
    return r;
}

__device__ __forceinline__ int zone_z(int z){ return z<30?0:(z<31?1:2); }
__device__ __forceinline__ int zone_hw(int h){ return h<24?0:(h<28?1:2); }

// ---------------- weight convert+transpose: w[K][N] fp32 -> wt[N][K] bf16 --
__global__ void wt_convert(const float* __restrict__ w, unsigned short* __restrict__ wt,
                           int K, int N)
{
    int idx = blockIdx.x*256 + threadIdx.x;
    if (idx >= K*N) return;
    int n = idx / K, k = idx - n*K;
    wt[idx] = f2bf(w[(size_t)k*N + n]);
}

// ---------------- relative position bias gather: bias_all[d][head][n][m] ---
__global__ void bias_precompute(const float* __restrict__ rpb,
                                float* __restrict__ bias_all)
{
    int d = blockIdx.x / HEADS, head = blockIdx.x % HEADS;
    int n = threadIdx.x;
    int i1 = n>>6, j1 = (n>>3)&7, k1 = n&7;
    const float* rp = rpb + d*675*HEADS;
    float* out = bias_all + ((size_t)blockIdx.x*128 + n)*128;
    for (int m = 0; m < 128; ++m){
        int i2 = m>>6, j2 = (m>>3)&7, k2 = m&7;
        int idx = (i1-i2+1)*225 + (j1-j2+7)*15 + (k1-k2+7);
        out[m] = rp[idx*HEADS + head];
    }
}

// ---------------- patch embed + LN: x -> e[pos][192], 4 positions/block ----
__global__ __launch_bounds__(192) void patch_embed_ln(
    const float* __restrict__ x, const float* __restrict__ pe_w,
    const float* __restrict__ pe_b, const float* __restrict__ gg,
    const float* __restrict__ bb, float* __restrict__ e)
{
    __shared__ float xs[4][128];
    __shared__ float red[4][2][3];
    int tid = threadIdx.x;
    int base = blockIdx.x*4;
    for (int idx = tid; idx < 512; idx += 192){
        int p = idx >> 7, t = idx & 127;
        int pos = base + p;
        int w = pos & 31, h = (pos>>5)&31, z = (pos>>10)&31, b = pos>>15;
        int c = t>>5, i = (t>>4)&1, j = (t>>2)&3, k = t&3;
        xs[p][t] = x[ (((size_t)(b*4+c)*64 + (z*2+i))*128 + (h*4+j))*128 + (w*4+k) ];
    }
    __syncthreads();
    float acca[4], accb[4];
    #pragma unroll
    for (int p=0;p<4;p++){ acca[p]=0.f; accb[p]=0.f; }
    const float* wrow = pe_w + tid*128;
    for (int t=0;t<128;t+=8){
        float4 w4a = *(const float4*)&wrow[t];
        float4 w4b = *(const float4*)&wrow[t+4];
        #pragma unroll
        for (int p=0;p<4;p++){
            float4 xa = *(const float4*)&xs[p][t];
            float4 xb = *(const float4*)&xs[p][t+4];
            acca[p] += xa.x*w4a.x + xa.y*w4a.y + xa.z*w4a.z + xa.w*w4a.w;
            accb[p] += xb.x*w4b.x + xb.y*w4b.y + xb.z*w4b.z + xb.w*w4b.w;
        }
    }
    float acc[4];
    float b0 = pe_b[tid];
    #pragma unroll
    for (int p=0;p<4;p++) acc[p] = acca[p] + accb[p] + b0;
    float s[4], s2[4];
    #pragma unroll
    for (int p=0;p<4;p++){ s[p]=acc[p]; s2[p]=acc[p]*acc[p]; }
    for (int off=32; off>=1; off>>=1){
        #pragma unroll
        for (int p=0;p<4;p++){ s[p]+=__shfl_xor(s[p],off); s2[p]+=__shfl_xor(s2[p],off); }
    }
    int wvid = tid>>6;
    if ((tid&63)==0){
        #pragma unroll
        for (int p=0;p<4;p++){ red[p][0][wvid]=s[p]; red[p][1][wvid]=s2[p]; }
    }
    __syncthreads();
    float gv = gg[tid], bv = bb[tid];
    #pragma unroll
    for (int p=0;p<4;p++){
        float sum = red[p][0][0]+red[p][0][1]+red[p][0][2];
        float sq  = red[p][1][0]+red[p][1][1]+red[p][1][2];
        float mean = sum*(1.f/192.f);
        float var = sq*(1.f/192.f) - mean*mean;
        float rstd = rsqrtf(var + 1e-5f);
        e[(size_t)(base+p)*CCH + tid] = (acc[p]-mean)*rstd*gv + bv;
    }
}

// ---------------- LayerNorm -> bf16; window_mode gathers shifted rows ------
__global__ __launch_bounds__(192) void ln_kernel(
    const float* __restrict__ in, unsigned short* __restrict__ outp,
    const float* __restrict__ gg, const float* __restrict__ bb,
    int window_mode, int shifted, int row0)
{
    int tid = threadIdx.x;
    int r = blockIdx.x + row0;
    int src;
    if (window_mode){
        int wb = r>>7, tok = r&127;
        int b = wb>>8, nw = wb&255;
        int zs = (nw>>4)*2 + (tok>>6);
        int hs = ((nw>>2)&3)*8 + ((tok>>3)&7);
        int ws = (nw&3)*8 + (tok&7);
        int z,h,w;
        if (shifted){ z=(zs+1)&31; h=(hs+4)&31; w=(ws+4)&31; }
        else        { z=zs; h=hs; w=ws; }
        src = ((b*32+z)*32+h)*32+w;
    } else src = r;
    float val = in[(size_t)src*CCH + tid];
    float s = val, s2 = val*val;
    for (int off=32; off>=1; off>>=1){ s += __shfl_xor(s,off); s2 += __shfl_xor(s2,off); }
    __shared__ float red[2][3];
    if ((tid&63)==0){ red[0][tid>>6]=s; red[1][tid>>6]=s2; }
    __syncthreads();
    float sum = red[0][0]+red[0][1]+red[0][2];
    float sq  = red[1][0]+red[1][1]+red[1][2];
    float mean = sum*(1.f/192.f);
    float rstd = rsqrtf(sq*(1.f/192.f) - mean*mean + 1e-5f);
    outp[(size_t)blockIdx.x*CCH + tid] = f2bf((val-mean)*rstd*gg[tid] + bb[tid]);
}

// ---------------- bf16 MFMA GEMM: C = A * Bt^T + bias ----------------------
template<int MODE>
__global__ __launch_bounds__(256) void gemm_mfma(
    const unsigned short* __restrict__ A, const unsigned short* __restrict__ Bt,
    const float* __restrict__ bias, void* __restrict__ Cout,
    int N, int K, int shifted, int row0)
{
    __shared__ unsigned short As[128*32];
    __shared__ unsigned short Bs[64*32];
    int t = threadIdx.x;
    int wave = t >> 6, lane = t & 63;
    int quad = lane >> 4, l16 = lane & 15;
    int m0 = blockIdx.y * 128, n0 = blockIdx.x * 64;

    f32x4 acc[2][4] = {};
    int ldrow = lane >> 2;
    int ldk   = (lane & 3) * 8;

    for (int k0 = 0; k0 < K; k0 += 32){
        #pragma unroll
        for (int s2 = 0; s2 < 2; ++s2){
            int s = wave*2 + s2;
            async16(A + (size_t)(m0 + s*16 + ldrow)*K + k0 + ldk, &As[s*512]);
        }
        async16(Bt + (size_t)(n0 + wave*16 + ldrow)*K + k0 + ldk, &Bs[wave*512]);
        __syncthreads();
        bf16x8 af[2], bfr[4];
        #pragma unroll
        for (int mt=0; mt<2; ++mt)
            af[mt] = *(const bf16x8*)&As[(wave*32 + mt*16 + l16)*32 + quad*8];
        #pragma unroll
        for (int nt=0; nt<4; ++nt)
            bfr[nt] = *(const bf16x8*)&Bs[(nt*16 + l16)*32 + quad*8];
        #pragma unroll
        for (int mt=0; mt<2; ++mt)
            #pragma unroll
            for (int nt=0; nt<4; ++nt)
                acc[mt][nt] = __builtin_amdgcn_mfma_f32_16x16x32_bf16(
                    af[mt], bfr[nt], acc[mt][nt], 0, 0, 0);
        __syncthreads();
    }

    float* Cf = (float*)Cout;
    unsigned short* Ch = (unsigned short*)Cout;
    #pragma unroll
    for (int mt=0; mt<2; ++mt){
        #pragma unroll
        for (int nt=0; nt<4; ++nt){
            #pragma unroll
            for (int r=0; r<4; ++r){
                int m = m0 + wave*32 + mt*16 + quad*4 + r;
                int n = n0 + nt*16 + l16;
                float v = acc[mt][nt][r] + bias[n];
                if (MODE==0){
                    Cf[(size_t)m*N + n] = v;
                } else if (MODE==1){
                    v = 0.5f*v*(1.f + erff(v*0.70710678118654752f));
                    Ch[(size_t)m*N + n] = f2bf(v);
                } else if (MODE==3){
                    Cf[(size_t)(m+row0)*N + n] += v;
                } else {
                    int mg = m + row0;
                    int wb = mg>>7, tok = mg&127;
                    int b = wb>>8, nw = wb&255;
                    int zs = (nw>>4)*2 + (tok>>6);
                    int hs = ((nw>>2)&3)*8 + ((tok>>3)&7);
                    int ws = (nw&3)*8 + (tok&7);
                    int z,h,w;
                    if (shifted){ z=(zs+1)&31; h=(hs+4)&31; w=(ws+4)&31; }
                    else        { z=zs; h=hs; w=ws; }
                    Cf[(size_t)(((b*32+z)*32+h)*32+w)*CCH + n] += v;
                }
            }
        }
    }
}

// ---------------- MFMA attention: one (window, head) per 256-thr block -----
// S = Q K^T via mfma (S in regs), softmax w/ 16-lane shfl, P->LDS bf16,
// O^T = mfma(A=V^T, B=P). Strides padded vs bank aliasing (36 / 132).
#define QKS 36
#define PVS 132
__global__ __launch_bounds__(256) void attn_mfma(
    const float* __restrict__ qkv, unsigned short* __restrict__ obuf,
    const float* __restrict__ bias_layer, int shifted, int wb0)
{
    __shared__ unsigned short Qs[128*QKS];
    __shared__ unsigned short Ks[128*QKS];
    __shared__ unsigned short Vt[32*PVS];
    __shared__ unsigned short Ps[128*PVS];
    __shared__ float linv[128];
    __shared__ int grp[128];

    int t = threadIdx.x;
    int wave = t >> 6, lane = t & 63;
    int quad = lane >> 4, l16 = lane & 15;
    int wb = blockIdx.x / HEADS;
    int head = blockIdx.x % HEADS;
    int nw = (wb + wb0) & 255;

    // ---- stage: 2 threads per token row; each does half the head-dim ----
    {
        int row = t >> 1, half = t & 1;
        const float* src = qkv + (size_t)(wb*128+row)*576 + head*32 + half*16;
        #pragma unroll
        for (int j=0;j<4;j++){
            float4 qv = *(const float4*)(src + j*4);
            float4 kv = *(const float4*)(src + 192 + j*4);
            float4 vv = *(const float4*)(src + 384 + j*4);
            *(ushort4*)&Qs[row*QKS + half*16 + j*4] = cvt4(qv);
            *(ushort4*)&Ks[row*QKS + half*16 + j*4] = cvt4(kv);
            int dbase = half*16 + j*4;
            Vt[(dbase+0)*PVS + row] = f2bf(vv.x);
            Vt[(dbase+1)*PVS + row] = f2bf(vv.y);
            Vt[(dbase+2)*PVS + row] = f2bf(vv.z);
            Vt[(dbase+3)*PVS + row] = f2bf(vv.w);
        }
    }
    if (t < 128 && shifted){
        int zs = (nw>>4)*2 + (t>>6);
        int hs = ((nw>>2)&3)*8 + ((t>>3)&7);
        int ws = (nw&3)*8 + (t&7);
        grp[t] = zone_z(zs)*9 + zone_hw(hs)*3 + zone_hw(ws);
    }
    __syncthreads();

    // ---- S = Q K^T : wave owns query rows [wave*32, wave*32+32) ----
    f32x4 sacc[2][8];
    #pragma unroll
    for (int mt=0;mt<2;mt++)
        #pragma unroll
        for (int nt=0;nt<8;nt++) sacc[mt][nt] = (f32x4){0.f,0.f,0.f,0.f};
    {
        bf16x8 af[2];
        #pragma unroll
        for (int mt=0;mt<2;mt++)
            af[mt] = ld_bf8(&Qs[(wave*32 + mt*16 + l16)*QKS + quad*8]);
        #pragma unroll
        for (int nt=0;nt<8;nt++){
            bf16x8 bf = ld_bf8(&Ks[(nt*16 + l16)*QKS + quad*8]);
            #pragma unroll
            for (int mt=0;mt<2;mt++)
                sacc[mt][nt] = __builtin_amdgcn_mfma_f32_16x16x32_bf16(
                    af[mt], bf, sacc[mt][nt], 0, 0, 0);
        }
    }

    // ---- softmax epilogue: scale+bias+mask, rowmax/rowsum, P->LDS ----
    const float scale = 0.17677669529663689f; // 32^-0.5
    #pragma unroll
    for (int mt=0;mt<2;mt++){
        #pragma unroll
        for (int r=0;r<4;r++){
            int row = wave*32 + mt*16 + quad*4 + r;
            const float* brow = bias_layer + (size_t)(head*128 + row)*128;
            int myg = shifted ? grp[row] : 0;
            float sv[8];
            float mloc = -1e30f;
            #pragma unroll
            for (int nt=0;nt<8;nt++){
                int col = nt*16 + l16;
                float s = sacc[mt][nt][r]*scale + brow[col];
                if (shifted && grp[col]!=myg) s -= 100.f;
                sv[nt] = s;
                mloc = fmaxf(mloc, s);
            }
            #pragma unroll
            for (int off=1;off<16;off<<=1) mloc = fmaxf(mloc, __shfl_xor(mloc, off));
            float lloc = 0.f;
            #pragma unroll
            for (int nt=0;nt<8;nt++){
                float p = __expf(sv[nt]-mloc);
                sv[nt] = p;
                lloc += p;
            }
            #pragma unroll
            for (int off=1;off<16;off<<=1) lloc += __shfl_xor(lloc, off);
            #pragma unroll
            for (int nt=0;nt<8;nt++)
                Ps[row*PVS + nt*16 + l16] = f2bf(sv[nt]);
            if (l16==0) linv[row] = 1.f/lloc;
        }
    }
    __syncthreads();

    // ---- O^T = V^T P^T : D[row=d][col=token], token tiles owned by wave ----
    f32x4 oacc[2][2];
    #pragma unroll
    for (int mt=0;mt<2;mt++)
        #pragma unroll
        for (int dt=0;dt<2;dt++) oacc[mt][dt] = (f32x4){0.f,0.f,0.f,0.f};
    #pragma unroll
    for (int ks=0;ks<4;ks++){
        bf16x8 av[2], pf[2];
        #pragma unroll
        for (int dt=0;dt<2;dt++)
            av[dt] = ld_bf8(&Vt[(dt*16 + l16)*PVS + ks*32 + quad*8]);
        #pragma unroll
        for (int mt=0;mt<2;mt++)
            pf[mt] = ld_bf8(&Ps[(wave*32 + mt*16 + l16)*PVS + ks*32 + quad*8]);
        #pragma unroll
        for (int mt=0;mt<2;mt++)
            #pragma unroll
            for (int dt=0;dt<2;dt++)
                oacc[mt][dt] = __builtin_amdgcn_mfma_f32_16x16x32_bf16(
                    av[dt], pf[mt], oacc[mt][dt], 0, 0, 0);
    }

    // ---- write O: lane holds token=l16(+tile), d=quad*4+r(+dt*16) ----
    #pragma unroll
    for (int mt=0;mt<2;mt++){
        int token = wave*32 + mt*16 + l16;
        float inv = linv[token];
        unsigned short* dst = obuf + (size_t)(wb*128+token)*CCH + head*32;
        #pragma unroll
        for (int dt=0;dt<2;dt++){
            ushort4 v4;
            v4.x = f2bf(oacc[mt][dt][0]*inv);
            v4.y = f2bf(oacc[mt][dt][1]*inv);
            v4.z = f2bf(oacc[mt][dt][2]*inv);
            v4.w = f2bf(oacc[mt][dt][3]*inv);
            *(ushort4*)&dst[dt*16 + quad*4] = v4;
        }
    }
}

// ---------------- reconstruction: e -> out, 8 positions/block --------------
__global__ __launch_bounds__(128) void recon_kernel(
    const float* __restrict__ e, const float* __restrict__ rec_w,
    const float* __restrict__ rec_b, float* __restrict__ out)
{
    __shared__ float es[8*192];
    int tid = threadIdx.x;
    int base = blockIdx.x*8;
    for (int idx = tid; idx < 8*192; idx += 128)
        es[idx] = e[(size_t)base*CCH + idx];
    __syncthreads();
    int o = tid>>5, i = (tid>>4)&1, j = (tid>>2)&3, k = tid&3;
    float acc[8];
    float rb = rec_b[o];
    #pragma unroll
    for (int p=0;p<8;p++) acc[p]=rb;
    for (int c=0;c<192;c++){
        float wv = rec_w[c*128 + tid];
        #pragma unroll
        for (int p=0;p<8;p++) acc[p] += es[p*192+c]*wv;
    }
    #pragma unroll
    for (int p=0;p<8;p++){
        int pos = base + p;
        int w = pos&31, h=(pos>>5)&31, z=(pos>>10)&31, b=pos>>15;
        out[ (((size_t)(b*4+o)*64 + (z*2+i))*128 + (h*4+j))*128 + (w*4+k) ] = acc[p];
    }
}

extern "C" void kernel_launch(void* const* d_in, const int* in_sizes, int n_in,
                              void* d_out, int out_size, void* d_ws, size_t ws_size,
                              hipStream_t stream) {
    const float* x       = (const float*)d_in[0];
    const float* pe_w    = (const float*)d_in[1];
    const float* pe_b    = (const float*)d_in[2];
    const float* pe_ln_g = (const float*)d_in[3];
    const float* pe_ln_b = (const float*)d_in[4];
    const float* ln1_g   = (const float*)d_in[5];
    const float* ln1_b   = (const float*)d_in[6];
    const float* qkv_w   = (const float*)d_in[7];
    const float* qkv_b   = (const float*)d_in[8];
    const float* proj_w  = (const float*)d_in[9];
    const float* proj_b  = (const float*)d_in[10];
    const float* rpb     = (const float*)d_in[11];
    const float* ln2_g   = (const float*)d_in[12];
    const float* ln2_b   = (const float*)d_in[13];
    const float* fc1_w   = (const float*)d_in[14];
    const float* fc1_b   = (const float*)d_in[15];
    const float* fc2_w   = (const float*)d_in[16];
    const float* fc2_b   = (const float*)d_in[17];
    const float* rec_w   = (const float*)d_in[18];
    const float* rec_b   = (const float*)d_in[19];
    float* out = (float*)d_out;
    char* wsb = (char*)d_ws;

    float*          e        = (float*)wsb;
    float*          bias_all = (float*)(wsb + 50331648);
    unsigned short* wt       = (unsigned short*)(wsb + 51904512);
    char*           stage    = wsb + 55443456;
    size_t scap = ws_size > 55443456 ? ws_size - 55443456 : 0;

    int WCH = 512;
    while (WCH > 16 && (size_t)WCH*128*3072 > scap) WCH >>= 1;
    int RCH = 65536;
    while (RCH > 2048 && (size_t)RCH*1920 > scap) RCH >>= 1;

    for (int d = 0; d < 4; ++d){
        unsigned short* wl = wt + (size_t)d*442368;
        wt_convert<<<(110592+255)/256, 256, 0, stream>>>(qkv_w  + (size_t)d*110592, wl,          192, 576);
        wt_convert<<<( 36864+255)/256, 256, 0, stream>>>(proj_w + (size_t)d* 36864, wl + 110592, 192, 192);
        wt_convert<<<(147456+255)/256, 256, 0, stream>>>(fc1_w  + (size_t)d*147456, wl + 147456, 192, 768);
        wt_convert<<<(147456+255)/256, 256, 0, stream>>>(fc2_w  + (size_t)d*147456, wl + 294912, 768, 192);
    }

    bias_precompute<<<24, 128, 0, stream>>>(rpb, bias_all);
    patch_embed_ln<<<16384, 192, 0, stream>>>(x, pe_w, pe_b, pe_ln_g, pe_ln_b, e);

    for (int d = 0; d < 4; ++d){
        int sh = d & 1;
        unsigned short* wl = wt + (size_t)d*442368;
        for (int w0 = 0; w0 < 512; w0 += WCH){
            int rows = WCH*128;
            unsigned short* bufc = (unsigned short*)stage;
            float*          qkvc = (float*)(stage + (size_t)rows*384);
            unsigned short* oc   = (unsigned short*)(stage + (size_t)rows*(384+2304));
            ln_kernel<<<rows, 192, 0, stream>>>(
                e, bufc, ln1_g + d*CCH, ln1_b + d*CCH, 1, sh, w0*128);
            gemm_mfma<0><<<dim3(9, rows/128), 256, 0, stream>>>(
                bufc, wl, qkv_b + d*3*CCH, qkvc, 576, 192, 0, 0);
            attn_mfma<<<WCH*HEADS, 256, 0, stream>>>(
                qkvc, oc, bias_all + (size_t)d*HEADS*128*128, sh, w0);
            gemm_mfma<2><<<dim3(3, rows/128), 256, 0, stream>>>(
                oc, wl + 110592, proj_b + d*CCH, e, 192, 192, sh, w0*128);
        }
        for (int r0 = 0; r0 < 65536; r0 += RCH){
            unsigned short* lnc = (unsigned short*)stage;
            unsigned short* hc  = (unsigned short*)(stage + (size_t)RCH*384);
            ln_kernel<<<RCH, 192, 0, stream>>>(
                e, lnc, ln2_g + d*CCH, ln2_b + d*CCH, 0, 0, r0);
            gemm_mfma<1><<<dim3(12, RCH/128), 256, 0, stream>>>(
                lnc, wl + 147456, fc1_b + d*4*CCH, hc, 768, 192, 0, 0);
            gemm_mfma<3><<<dim3(3, RCH/128), 256, 0, stream>>>(
                hc, wl + 294912, fc2_b + d*CCH, e, 192, 768, 0, r0);
        }
    }
    recon_kernel<<<8192, 128, 0, stream>>>(e, rec_w, rec_b, out);
}

// Round 5
// 1724.902 us; speedup vs baseline: 2.9806x; 1.1761x over previous
//
#include <hip/hip_runtime.h>
#include <math.h>

// SwinDecoder on MI355X. Round 5: MFMA patch-embed(+fused LN) and recon;
// qkv path bf16 end-to-end.
// ws layout (bytes):
//   e        : 0          .. 50,331,648   fp32 [65536][192]
//   bias_all : 50,331,648 .. 51,904,512   fp32 [4][6][128][128]
//   wt       : 51,904,512 .. 55,541,760   bf16 weights (4 layers + pe + rec)
//   stage    : 55,541,760 .. (chunked; 1920 B/row both phases)

#define CCH 192
#define HEADS 6

typedef __attribute__((ext_vector_type(8))) short bf16x8;
typedef __attribute__((ext_vector_type(4))) float f32x4;

__device__ __forceinline__ unsigned short f2bf(float f){
    union { float f; unsigned int u; } x; x.f = f;
    unsigned int r = (x.u + 0x7fffu + ((x.u >> 16) & 1u)) >> 16;
    return (unsigned short)r;
}

__device__ __forceinline__ void async16(const void* g, void* l){
    __builtin_amdgcn_global_load_lds(
        (const __attribute__((address_space(1))) void*)g,
        (__attribute__((address_space(3))) void*)l, 16, 0, 0);
}

__device__ __forceinline__ bf16x8 ld_bf8(const unsigned short* p){
    ushort4 lo = *(const ushort4*)p;
    ushort4 hi = *(const ushort4*)(p+4);
    bf16x8 r;
    r[0]=(short)lo.x; r[1]=(short)lo.y; r[2]=(short)lo.z; r[3]=(short)lo.w;
    r[4]=(short)hi.x; r[5]=(short)hi.y; r[6]=(short)hi.z; r[7]=(short)hi.w;
    return r;
}

__device__ __forceinline__ ushort4 cvt4(float4 v){
    ushort4 r; r.x=f2bf(v.x); r.y=f2bf(v.y); r.z=f2bf(v.z); r.w=f2bf(v.w);
    return r;
}

__device__ __forceinline__ int zone_z(int z){ return z<30?0:(z<31?1:2); }
__device__ __forceinline__ int zone_hw(int h){ return h<24?0:(h<28?1:2); }

// ---------------- weight convert+transpose: w[K][N] fp32 -> wt[N][K] bf16 --
__global__ void wt_convert(const float* __restrict__ w, unsigned short* __restrict__ wt,
                           int K, int N)
{
    int idx = blockIdx.x*256 + threadIdx.x;
    if (idx >= K*N) return;
    int n = idx / K, k = idx - n*K;
    wt[idx] = f2bf(w[(size_t)k*N + n]);
}

// ---------------- plain fp32 -> bf16 convert -------------------------------
__global__ void pe_conv(const float* __restrict__ w, unsigned short* __restrict__ o, int n)
{
    int i = blockIdx.x*256 + threadIdx.x;
    if (i < n) o[i] = f2bf(w[i]);
}

// ---------------- relative position bias gather: bias_all[d][head][n][m] ---
__global__ void bias_precompute(const float* __restrict__ rpb,
                                float* __restrict__ bias_all)
{
    int d = blockIdx.x / HEADS, head = blockIdx.x % HEADS;
    int n = threadIdx.x;
    int i1 = n>>6, j1 = (n>>3)&7, k1 = n&7;
    const float* rp = rpb + d*675*HEADS;
    float* out = bias_all + ((size_t)blockIdx.x*128 + n)*128;
    for (int m = 0; m < 128; ++m){
        int i2 = m>>6, j2 = (m>>3)&7, k2 = m&7;
        int idx = (i1-i2+1)*225 + (j1-j2+7)*15 + (k1-k2+7);
        out[m] = rp[idx*HEADS + head];
    }
}

// ---------------- patch embed via MFMA, LN fused in epilogue ---------------
// A: gathered x patches [64 rows][128 K] bf16 (stride 132); B: pe_w bf16
// [192][128] staged in two 96-col phases. e out fp32.
__global__ __launch_bounds__(256) void patch_embed_mfma(
    const float* __restrict__ x, const unsigned short* __restrict__ pwb,
    const float* __restrict__ pe_b, const float* __restrict__ gg,
    const float* __restrict__ bb, float* __restrict__ e)
{
    __shared__ unsigned short As[64*132];   // 16,896 B
    __shared__ unsigned short Bs[96*132];   // 25,344 B
    int t = threadIdx.x;
    int wave = t>>6, lane = t&63, quad = lane>>4, l16 = lane&15;
    int m0 = blockIdx.x*64;

    // stage A: patch gather + bf16
    {
        int row = t & 63, cg = (t>>6)*8;
        int pos = m0 + row;
        int w = pos&31, h=(pos>>5)&31, z=(pos>>10)&31, b=pos>>15;
        #pragma unroll
        for (int cc=0; cc<8; ++cc){
            int chunk = cg + cc;
            int c = chunk>>3, i=(chunk>>2)&1, j=chunk&3;
            float4 v = *(const float4*)&x[ (((size_t)(b*4+c)*64 + (z*2+i))*128 + (h*4+j))*128 + w*4 ];
            *(ushort4*)&As[row*132 + chunk*4] = cvt4(v);
        }
    }

    f32x4 acc[12] = {};
    #pragma unroll
    for (int ph = 0; ph < 2; ++ph){
        if (ph) __syncthreads();   // phase-0 compute must finish reading Bs
        // stage B half: cols [ph*96, ph*96+96)
        #pragma unroll
        for (int it=0; it<6; ++it){
            int g = it*256 + t;          // 0..1535
            int row = g >> 4, c8 = g & 15;
            const unsigned short* src = pwb + ((size_t)(ph*96+row))*128 + c8*8;
            uint4 u = *(const uint4*)src;
            unsigned short* dst = &Bs[row*132 + c8*8];
            *(uint2*)dst       = make_uint2(u.x, u.y);
            *(uint2*)(dst+4)   = make_uint2(u.z, u.w);
        }
        __syncthreads();
        #pragma unroll
        for (int ks=0; ks<4; ++ks){
            bf16x8 af = ld_bf8(&As[(wave*16 + l16)*132 + ks*32 + quad*8]);
            #pragma unroll
            for (int nt=0; nt<6; ++nt){
                bf16x8 bf = ld_bf8(&Bs[(nt*16 + l16)*132 + ks*32 + quad*8]);
                acc[ph*6+nt] = __builtin_amdgcn_mfma_f32_16x16x32_bf16(
                    af, bf, acc[ph*6+nt], 0, 0, 0);
            }
        }
    }

    // epilogue: +pe_b, LN across 192 cols (12 nt x 16 lanes), write fp32 e
    float pb[12], gv[12], bv[12];
    #pragma unroll
    for (int nt=0; nt<12; ++nt){
        int col = nt*16 + l16;
        pb[nt] = pe_b[col]; gv[nt] = gg[col]; bv[nt] = bb[col];
    }
    #pragma unroll
    for (int r=0; r<4; ++r){
        int row = wave*16 + quad*4 + r;
        int pos = m0 + row;
        float sv[12], s1 = 0.f, s2 = 0.f;
        #pragma unroll
        for (int nt=0; nt<12; ++nt){
            float v = acc[nt][r] + pb[nt];
            sv[nt] = v; s1 += v; s2 += v*v;
        }
        #pragma unroll
        for (int off=1; off<16; off<<=1){
            s1 += __shfl_xor(s1, off); s2 += __shfl_xor(s2, off);
        }
        float mean = s1*(1.f/192.f);
        float rstd = rsqrtf(s2*(1.f/192.f) - mean*mean + 1e-5f);
        #pragma unroll
        for (int nt=0; nt<12; ++nt){
            int col = nt*16 + l16;
            e[(size_t)pos*CCH + col] = (sv[nt]-mean)*rstd*gv[nt] + bv[nt];
        }
    }
}

// ---------------- reconstruction via MFMA ----------------------------------
// A = e fp32->bf16 [64 rows][192 K] (stride 196); B = rec_wt bf16 [128][192]
// staged in two 64-col phases; scatter-write fp32 out.
__global__ __launch_bounds__(256) void recon_mfma(
    const float* __restrict__ e, const unsigned short* __restrict__ rwt,
    const float* __restrict__ rec_b, float* __restrict__ out)
{
    __shared__ unsigned short As[64*196];   // 25,088 B
    __shared__ unsigned short Bs[64*196];   // 25,088 B
    int t = threadIdx.x;
    int wave = t>>6, lane = t&63, quad = lane>>4, l16 = lane&15;
    int m0 = blockIdx.x*64;

    // stage A: e -> bf16, flat float4 iteration
    #pragma unroll
    for (int it=0; it<12; ++it){
        int g = it*256 + t;            // 0..3071
        int row = g/48, c4 = g - row*48;
        float4 v = *(const float4*)&e[(size_t)(m0+row)*CCH + c4*4];
        *(ushort4*)&As[row*196 + c4*4] = cvt4(v);
    }

    f32x4 acc[8] = {};
    #pragma unroll
    for (int ph = 0; ph < 2; ++ph){
        if (ph) __syncthreads();
        #pragma unroll
        for (int it=0; it<6; ++it){
            int g = it*256 + t;        // 0..1535
            int row = g/24, c8 = g - row*24;
            const unsigned short* src = rwt + ((size_t)(ph*64+row))*192 + c8*8;
            uint4 u = *(const uint4*)src;
            unsigned short* dst = &Bs[row*196 + c8*8];
            *(uint2*)dst     = make_uint2(u.x, u.y);
            *(uint2*)(dst+4) = make_uint2(u.z, u.w);
        }
        __syncthreads();
        #pragma unroll
        for (int ks=0; ks<6; ++ks){
            bf16x8 af = ld_bf8(&As[(wave*16 + l16)*196 + ks*32 + quad*8]);
            #pragma unroll
            for (int nt=0; nt<4; ++nt){
                bf16x8 bf = ld_bf8(&Bs[(nt*16 + l16)*196 + ks*32 + quad*8]);
                acc[ph*4+nt] = __builtin_amdgcn_mfma_f32_16x16x32_bf16(
                    af, bf, acc[ph*4+nt], 0, 0, 0);
            }
        }
    }

    #pragma unroll
    for (int nt=0; nt<8; ++nt){
        int col = nt*16 + l16;
        int o = col>>5, i = (col>>4)&1, j = (col>>2)&3, k = col&3;
        float rb = rec_b[o];
        #pragma unroll
        for (int r=0; r<4; ++r){
            int pos = m0 + wave*16 + quad*4 + r;
            int w = pos&31, h=(pos>>5)&31, z=(pos>>10)&31, b=pos>>15;
            out[ (((size_t)(b*4+o)*64 + (z*2+i))*128 + (h*4+j))*128 + (w*4+k) ]
                = acc[nt][r] + rb;
        }
    }
}

// ---------------- LayerNorm -> bf16; window_mode gathers shifted rows ------
__global__ __launch_bounds__(192) void ln_kernel(
    const float* __restrict__ in, unsigned short* __restrict__ outp,
    const float* __restrict__ gg, const float* __restrict__ bb,
    int window_mode, int shifted, int row0)
{
    int tid = threadIdx.x;
    int r = blockIdx.x + row0;
    int src;
    if (window_mode){
        int wb = r>>7, tok = r&127;
        int b = wb>>8, nw = wb&255;
        int zs = (nw>>4)*2 + (tok>>6);
        int hs = ((nw>>2)&3)*8 + ((tok>>3)&7);
        int ws = (nw&3)*8 + (tok&7);
        int z,h,w;
        if (shifted){ z=(zs+1)&31; h=(hs+4)&31; w=(ws+4)&31; }
        else        { z=zs; h=hs; w=ws; }
        src = ((b*32+z)*32+h)*32+w;
    } else src = r;
    float val = in[(size_t)src*CCH + tid];
    float s = val, s2 = val*val;
    for (int off=32; off>=1; off>>=1){ s += __shfl_xor(s,off); s2 += __shfl_xor(s2,off); }
    __shared__ float red[2][3];
    if ((tid&63)==0){ red[0][tid>>6]=s; red[1][tid>>6]=s2; }
    __syncthreads();
    float sum = red[0][0]+red[0][1]+red[0][2];
    float sq  = red[1][0]+red[1][1]+red[1][2];
    float mean = sum*(1.f/192.f);
    float rstd = rsqrtf(sq*(1.f/192.f) - mean*mean + 1e-5f);
    outp[(size_t)blockIdx.x*CCH + tid] = f2bf((val-mean)*rstd*gg[tid] + bb[tid]);
}

// ---------------- bf16 MFMA GEMM: C = A * Bt^T + bias ----------------------
// MODE 0: fp32 out. 1: gelu->bf16. 2: window-reverse residual add (fp32 e).
// MODE 3: fp32 += (global rows). 4: plain bf16 out.
template<int MODE>
__global__ __launch_bounds__(256) void gemm_mfma(
    const unsigned short* __restrict__ A, const unsigned short* __restrict__ Bt,
    const float* __restrict__ bias, void* __restrict__ Cout,
    int N, int K, int shifted, int row0)
{
    __shared__ unsigned short As[128*32];
    __shared__ unsigned short Bs[64*32];
    int t = threadIdx.x;
    int wave = t >> 6, lane = t & 63;
    int quad = lane >> 4, l16 = lane & 15;
    int m0 = blockIdx.y * 128, n0 = blockIdx.x * 64;

    f32x4 acc[2][4] = {};
    int ldrow = lane >> 2;
    int ldk   = (lane & 3) * 8;

    for (int k0 = 0; k0 < K; k0 += 32){
        #pragma unroll
        for (int s2 = 0; s2 < 2; ++s2){
            int s = wave*2 + s2;
            async16(A + (size_t)(m0 + s*16 + ldrow)*K + k0 + ldk, &As[s*512]);
        }
        async16(Bt + (size_t)(n0 + wave*16 + ldrow)*K + k0 + ldk, &Bs[wave*512]);
        __syncthreads();
        bf16x8 af[2], bfr[4];
        #pragma unroll
        for (int mt=0; mt<2; ++mt)
            af[mt] = *(const bf16x8*)&As[(wave*32 + mt*16 + l16)*32 + quad*8];
        #pragma unroll
        for (int nt=0; nt<4; ++nt)
            bfr[nt] = *(const bf16x8*)&Bs[(nt*16 + l16)*32 + quad*8];
        #pragma unroll
        for (int mt=0; mt<2; ++mt)
            #pragma unroll
            for (int nt=0; nt<4; ++nt)
                acc[mt][nt] = __builtin_amdgcn_mfma_f32_16x16x32_bf16(
                    af[mt], bfr[nt], acc[mt][nt], 0, 0, 0);
        __syncthreads();
    }

    float* Cf = (float*)Cout;
    unsigned short* Ch = (unsigned short*)Cout;
    #pragma unroll
    for (int mt=0; mt<2; ++mt){
        #pragma unroll
        for (int nt=0; nt<4; ++nt){
            #pragma unroll
            for (int r=0; r<4; ++r){
                int m = m0 + wave*32 + mt*16 + quad*4 + r;
                int n = n0 + nt*16 + l16;
                float v = acc[mt][nt][r] + bias[n];
                if (MODE==0){
                    Cf[(size_t)m*N + n] = v;
                } else if (MODE==4){
                    Ch[(size_t)m*N + n] = f2bf(v);
                } else if (MODE==1){
                    v = 0.5f*v*(1.f + erff(v*0.70710678118654752f));
                    Ch[(size_t)m*N + n] = f2bf(v);
                } else if (MODE==3){
                    Cf[(size_t)(m+row0)*N + n] += v;
                } else {
                    int mg = m + row0;
                    int wb = mg>>7, tok = mg&127;
                    int b = wb>>8, nw = wb&255;
                    int zs = (nw>>4)*2 + (tok>>6);
                    int hs = ((nw>>2)&3)*8 + ((tok>>3)&7);
                    int ws = (nw&3)*8 + (tok&7);
                    int z,h,w;
                    if (shifted){ z=(zs+1)&31; h=(hs+4)&31; w=(ws+4)&31; }
                    else        { z=zs; h=hs; w=ws; }
                    Cf[(size_t)(((b*32+z)*32+h)*32+w)*CCH + n] += v;
                }
            }
        }
    }
}

// ---------------- MFMA attention: one (window, head) per 256-thr block -----
// qkv is bf16. S = Q K^T via mfma, softmax w/ 16-lane shfl, P->LDS bf16,
// O^T = mfma(A=V^T, B=P).
#define QKS 36
#define PVS 132
__global__ __launch_bounds__(256) void attn_mfma(
    const unsigned short* __restrict__ qkv, unsigned short* __restrict__ obuf,
    const float* __restrict__ bias_layer, int shifted, int wb0)
{
    __shared__ unsigned short Qs[128*QKS];
    __shared__ unsigned short Ks[128*QKS];
    __shared__ unsigned short Vt[32*PVS];
    __shared__ unsigned short Ps[128*PVS];
    __shared__ float linv[128];
    __shared__ int grp[128];

    int t = threadIdx.x;
    int wave = t >> 6, lane = t & 63;
    int quad = lane >> 4, l16 = lane & 15;
    int wb = blockIdx.x / HEADS;
    int head = blockIdx.x % HEADS;
    int nw = (wb + wb0) & 255;

    {
        int row = t >> 1, half = t & 1;
        const unsigned short* src = qkv + (size_t)(wb*128+row)*576 + head*32 + half*16;
        #pragma unroll
        for (int j=0;j<4;j++){
            ushort4 qv = *(const ushort4*)(src + j*4);
            ushort4 kv = *(const ushort4*)(src + 192 + j*4);
            ushort4 vv = *(const ushort4*)(src + 384 + j*4);
            *(ushort4*)&Qs[row*QKS + half*16 + j*4] = qv;
            *(ushort4*)&Ks[row*QKS + half*16 + j*4] = kv;
            int dbase = half*16 + j*4;
            Vt[(dbase+0)*PVS + row] = vv.x;
            Vt[(dbase+1)*PVS + row] = vv.y;
            Vt[(dbase+2)*PVS + row] = vv.z;
            Vt[(dbase+3)*PVS + row] = vv.w;
        }
    }
    if (t < 128 && shifted){
        int zs = (nw>>4)*2 + (t>>6);
        int hs = ((nw>>2)&3)*8 + ((t>>3)&7);
        int ws = (nw&3)*8 + (t&7);
        grp[t] = zone_z(zs)*9 + zone_hw(hs)*3 + zone_hw(ws);
    }
    __syncthreads();

    f32x4 sacc[2][8];
    #pragma unroll
    for (int mt=0;mt<2;mt++)
        #pragma unroll
        for (int nt=0;nt<8;nt++) sacc[mt][nt] = (f32x4){0.f,0.f,0.f,0.f};
    {
        bf16x8 af[2];
        #pragma unroll
        for (int mt=0;mt<2;mt++)
            af[mt] = ld_bf8(&Qs[(wave*32 + mt*16 + l16)*QKS + quad*8]);
        #pragma unroll
        for (int nt=0;nt<8;nt++){
            bf16x8 bf = ld_bf8(&Ks[(nt*16 + l16)*QKS + quad*8]);
            #pragma unroll
            for (int mt=0;mt<2;mt++)
                sacc[mt][nt] = __builtin_amdgcn_mfma_f32_16x16x32_bf16(
                    af[mt], bf, sacc[mt][nt], 0, 0, 0);
        }
    }

    const float scale = 0.17677669529663689f;
    #pragma unroll
    for (int mt=0;mt<2;mt++){
        #pragma unroll
        for (int r=0;r<4;r++){
            int row = wave*32 + mt*16 + quad*4 + r;
            const float* brow = bias_layer + (size_t)(head*128 + row)*128;
            int myg = shifted ? grp[row] : 0;
            float sv[8];
            float mloc = -1e30f;
            #pragma unroll
            for (int nt=0;nt<8;nt++){
                int col = nt*16 + l16;
                float s = sacc[mt][nt][r]*scale + brow[col];
                if (shifted && grp[col]!=myg) s -= 100.f;
                sv[nt] = s;
                mloc = fmaxf(mloc, s);
            }
            #pragma unroll
            for (int off=1;off<16;off<<=1) mloc = fmaxf(mloc, __shfl_xor(mloc, off));
            float lloc = 0.f;
            #pragma unroll
            for (int nt=0;nt<8;nt++){
                float p = __expf(sv[nt]-mloc);
                sv[nt] = p;
                lloc += p;
            }
            #pragma unroll
            for (int off=1;off<16;off<<=1) lloc += __shfl_xor(lloc, off);
            #pragma unroll
            for (int nt=0;nt<8;nt++)
                Ps[row*PVS + nt*16 + l16] = f2bf(sv[nt]);
            if (l16==0) linv[row] = 1.f/lloc;
        }
    }
    __syncthreads();

    f32x4 oacc[2][2];
    #pragma unroll
    for (int mt=0;mt<2;mt++)
        #pragma unroll
        for (int dt=0;dt<2;dt++) oacc[mt][dt] = (f32x4){0.f,0.f,0.f,0.f};
    #pragma unroll
    for (int ks=0;ks<4;ks++){
        bf16x8 av[2], pf[2];
        #pragma unroll
        for (int dt=0;dt<2;dt++)
            av[dt] = ld_bf8(&Vt[(dt*16 + l16)*PVS + ks*32 + quad*8]);
        #pragma unroll
        for (int mt=0;mt<2;mt++)
            pf[mt] = ld_bf8(&Ps[(wave*32 + mt*16 + l16)*PVS + ks*32 + quad*8]);
        #pragma unroll
        for (int mt=0;mt<2;mt++)
            #pragma unroll
            for (int dt=0;dt<2;dt++)
                oacc[mt][dt] = __builtin_amdgcn_mfma_f32_16x16x32_bf16(
                    av[dt], pf[mt], oacc[mt][dt], 0, 0, 0);
    }

    #pragma unroll
    for (int mt=0;mt<2;mt++){
        int token = wave*32 + mt*16 + l16;
        float inv = linv[token];
        unsigned short* dst = obuf + (size_t)(wb*128+token)*CCH + head*32;
        #pragma unroll
        for (int dt=0;dt<2;dt++){
            ushort4 v4;
            v4.x = f2bf(oacc[mt][dt][0]*inv);
            v4.y = f2bf(oacc[mt][dt][1]*inv);
            v4.z = f2bf(oacc[mt][dt][2]*inv);
            v4.w = f2bf(oacc[mt][dt][3]*inv);
            *(ushort4*)&dst[dt*16 + quad*4] = v4;
        }
    }
}

extern "C" void kernel_launch(void* const* d_in, const int* in_sizes, int n_in,
                              void* d_out, int out_size, void* d_ws, size_t ws_size,
                              hipStream_t stream) {
    const float* x       = (const float*)d_in[0];
    const float* pe_w    = (const float*)d_in[1];
    const float* pe_b    = (const float*)d_in[2];
    const float* pe_ln_g = (const float*)d_in[3];
    const float* pe_ln_b = (const float*)d_in[4];
    const float* ln1_g   = (const float*)d_in[5];
    const float* ln1_b   = (const float*)d_in[6];
    const float* qkv_w   = (const float*)d_in[7];
    const float* qkv_b   = (const float*)d_in[8];
    const float* proj_w  = (const float*)d_in[9];
    const float* proj_b  = (const float*)d_in[10];
    const float* rpb     = (const float*)d_in[11];
    const float* ln2_g   = (const float*)d_in[12];
    const float* ln2_b   = (const float*)d_in[13];
    const float* fc1_w   = (const float*)d_in[14];
    const float* fc1_b   = (const float*)d_in[15];
    const float* fc2_w   = (const float*)d_in[16];
    const float* fc2_b   = (const float*)d_in[17];
    const float* rec_w   = (const float*)d_in[18];
    const float* rec_b   = (const float*)d_in[19];
    float* out = (float*)d_out;
    char* wsb = (char*)d_ws;

    float*          e        = (float*)wsb;
    float*          bias_all = (float*)(wsb + 50331648);
    unsigned short* wt       = (unsigned short*)(wsb + 51904512);
    unsigned short* pwb      = wt + 1769472;        // pe_w bf16 [192][128]
    unsigned short* rwt      = wt + 1794048;        // rec_w^T bf16 [128][192]
    char*           stage    = wsb + 55541760;
    size_t scap = ws_size > 55541760 ? ws_size - 55541760 : 0;

    int WCH = 512;
    while (WCH > 16 && (size_t)WCH*128*1920 > scap) WCH >>= 1;
    int RCH = 65536;
    while (RCH > 2048 && (size_t)RCH*1920 > scap) RCH >>= 1;

    for (int d = 0; d < 4; ++d){
        unsigned short* wl = wt + (size_t)d*442368;
        wt_convert<<<(110592+255)/256, 256, 0, stream>>>(qkv_w  + (size_t)d*110592, wl,          192, 576);
        wt_convert<<<( 36864+255)/256, 256, 0, stream>>>(proj_w + (size_t)d* 36864, wl + 110592, 192, 192);
        wt_convert<<<(147456+255)/256, 256, 0, stream>>>(fc1_w  + (size_t)d*147456, wl + 147456, 192, 768);
        wt_convert<<<(147456+255)/256, 256, 0, stream>>>(fc2_w  + (size_t)d*147456, wl + 294912, 768, 192);
    }
    pe_conv<<<96, 256, 0, stream>>>(pe_w, pwb, 24576);
    wt_convert<<<96, 256, 0, stream>>>(rec_w, rwt, 192, 128);

    bias_precompute<<<24, 128, 0, stream>>>(rpb, bias_all);
    patch_embed_mfma<<<1024, 256, 0, stream>>>(x, pwb, pe_b, pe_ln_g, pe_ln_b, e);

    for (int d = 0; d < 4; ++d){
        int sh = d & 1;
        unsigned short* wl = wt + (size_t)d*442368;
        for (int w0 = 0; w0 < 512; w0 += WCH){
            int rows = WCH*128;
            unsigned short* bufc = (unsigned short*)stage;
            unsigned short* qkvc = (unsigned short*)(stage + (size_t)rows*384);
            unsigned short* oc   = (unsigned short*)(stage + (size_t)rows*1536);
            ln_kernel<<<rows, 192, 0, stream>>>(
                e, bufc, ln1_g + d*CCH, ln1_b + d*CCH, 1, sh, w0*128);
            gemm_mfma<4><<<dim3(9, rows/128), 256, 0, stream>>>(
                bufc, wl, qkv_b + d*3*CCH, qkvc, 576, 192, 0, 0);
            attn_mfma<<<WCH*HEADS, 256, 0, stream>>>(
                qkvc, oc, bias_all + (size_t)d*HEADS*128*128, sh, w0);
            gemm_mfma<2><<<dim3(3, rows/128), 256, 0, stream>>>(
                oc, wl + 110592, proj_b + d*CCH, e, 192, 192, sh, w0*128);
        }
        for (int r0 = 0; r0 < 65536; r0 += RCH){
            unsigned short* lnc = (unsigned short*)stage;
            unsigned short* hc  = (unsigned short*)(stage + (size_t)RCH*384);
            ln_kernel<<<RCH, 192, 0, stream>>>(
                e, lnc, ln2_g + d*CCH, ln2_b + d*CCH, 0, 0, r0);
            gemm_mfma<1><<<dim3(12, RCH/128), 256, 0, stream>>>(
                lnc, wl + 147456, fc1_b + d*4*CCH, hc, 768, 192, 0, 0);
            gemm_mfma<3><<<dim3(3, RCH/128), 256, 0, stream>>>(
                hc, wl + 294912, fc2_b + d*CCH, e, 192, 768, 0, r0);
        }
    }
    recon_mfma<<<1024, 256, 0, stream>>>(e, rwt, rec_b, out);
}

// Round 6
// 1497.866 us; speedup vs baseline: 3.4323x; 1.1516x over previous
//
#include <hip/hip_runtime.h>
#include <math.h>

// SwinDecoder on MI355X. Round 6: latency-restructured attention.
// - qkv GEMM writes Q|K row-major [tok][384] and V transposed [win][d][tok]
// - attention stages K/Vt/bias via global_load_lds into MFMA-interleaved
//   LDS layouts (conflict-free ds_read_b128 fragments), Q direct from global,
//   bias pre-converted bf16 staged into the P region, single barrier.
// ws layout (bytes):
//   e        : 0          .. 50,331,648   fp32 [65536][192]
//   bias_il  : 50,331,648 .. 51,118,080   bf16 interleaved [4][6][16384]
//   wt       : 51,904,512 .. 55,541,760   bf16 weights (4 layers + pe + rec)
//   stage    : 55,541,760 .. (chunked; 1920 B/row)

#define CCH 192
#define HEADS 6

typedef __attribute__((ext_vector_type(8))) short bf16x8;
typedef __attribute__((ext_vector_type(4))) float f32x4;

__device__ __forceinline__ unsigned short f2bf(float f){
    union { float f; unsigned int u; } x; x.f = f;
    unsigned int r = (x.u + 0x7fffu + ((x.u >> 16) & 1u)) >> 16;
    return (unsigned short)r;
}
__device__ __forceinline__ float bf2f(unsigned short h){
    union { unsigned int u; float f; } x; x.u = ((unsigned int)h)<<16;
    return x.f;
}

__device__ __forceinline__ void async16(const void* g, void* l){
    __builtin_amdgcn_global_load_lds(
        (const __attribute__((address_space(1))) void*)g,
        (__attribute__((address_space(3))) void*)l, 16, 0, 0);
}

__device__ __forceinline__ ushort4 cvt4(float4 v){
    ushort4 r; r.x=f2bf(v.x); r.y=f2bf(v.y); r.z=f2bf(v.z); r.w=f2bf(v.w);
    return r;
}

__device__ __forceinline__ int zone_z(int z){ return z<30?0:(z<31?1:2); }
__device__ __forceinline__ int zone_hw(int h){ return h<24?0:(h<28?1:2); }

// ---------------- weight convert+transpose: w[K][N] fp32 -> wt[N][K] bf16 --
__global__ void wt_convert(const float* __restrict__ w, unsigned short* __restrict__ wt,
                           int K, int N)
{
    int idx = blockIdx.x*256 + threadIdx.x;
    if (idx >= K*N) return;
    int n = idx / K, k = idx - n*K;
    wt[idx] = f2bf(w[(size_t)k*N + n]);
}

// ---------------- plain fp32 -> bf16 convert -------------------------------
__global__ void pe_conv(const float* __restrict__ w, unsigned short* __restrict__ o, int n)
{
    int i = blockIdx.x*256 + threadIdx.x;
    if (i < n) o[i] = f2bf(w[i]);
}

// ---- rel-pos bias -> bf16 in MFMA-interleaved layout ----------------------
// off(n,m) = (n>>4)*2048 + (m>>5)*512 + ((m>>3)&3)*128 + (n&15)*8 + (m&7)
__global__ void bias_precompute(const float* __restrict__ rpb,
                                unsigned short* __restrict__ bias_il)
{
    int d = blockIdx.x / HEADS, head = blockIdx.x % HEADS;
    int n = threadIdx.x;
    int i1 = n>>6, j1 = (n>>3)&7, k1 = n&7;
    const float* rp = rpb + d*675*HEADS;
    unsigned short* out = bias_il + (size_t)blockIdx.x*16384;
    int rbase = (n>>4)*2048 + (n&15)*8;
    for (int m = 0; m < 128; ++m){
        int i2 = m>>6, j2 = (m>>3)&7, k2 = m&7;
        int idx = (i1-i2+1)*225 + (j1-j2+7)*15 + (k1-k2+7);
        int off = rbase + (m>>5)*512 + ((m>>3)&3)*128 + (m&7);
        out[off] = f2bf(rp[idx*HEADS + head]);
    }
}

// ---------------- patch embed via MFMA, LN fused in epilogue ---------------
__global__ __launch_bounds__(256) void patch_embed_mfma(
    const float* __restrict__ x, const unsigned short* __restrict__ pwb,
    const float* __restrict__ pe_b, const float* __restrict__ gg,
    const float* __restrict__ bb, float* __restrict__ e)
{
    __shared__ __align__(16) unsigned short As[64*132];
    __shared__ __align__(16) unsigned short Bs[96*132];
    int t = threadIdx.x;
    int wave = t>>6, lane = t&63, quad = lane>>4, l16 = lane&15;
    int m0 = blockIdx.x*64;

    {
        int row = t & 63, cg = (t>>6)*8;
        int pos = m0 + row;
        int w = pos&31, h=(pos>>5)&31, z=(pos>>10)&31, b=pos>>15;
        #pragma unroll
        for (int cc=0; cc<8; ++cc){
            int chunk = cg + cc;
            int c = chunk>>3, i=(chunk>>2)&1, j=chunk&3;
            float4 v = *(const float4*)&x[ (((size_t)(b*4+c)*64 + (z*2+i))*128 + (h*4+j))*128 + w*4 ];
            *(ushort4*)&As[row*132 + chunk*4] = cvt4(v);
        }
    }

    f32x4 acc[12] = {};
    #pragma unroll
    for (int ph = 0; ph < 2; ++ph){
        if (ph) __syncthreads();
        #pragma unroll
        for (int it=0; it<6; ++it){
            int g = it*256 + t;
            int row = g >> 4, c8 = g & 15;
            const unsigned short* src = pwb + ((size_t)(ph*96+row))*128 + c8*8;
            uint4 u = *(const uint4*)src;
            unsigned short* dst = &Bs[row*132 + c8*8];
            *(uint2*)dst       = make_uint2(u.x, u.y);
            *(uint2*)(dst+4)   = make_uint2(u.z, u.w);
        }
        __syncthreads();
        #pragma unroll
        for (int ks=0; ks<4; ++ks){
            bf16x8 af = *(const bf16x8*)&As[(wave*16 + l16)*132 + ks*32 + quad*8];
            #pragma unroll
            for (int nt=0; nt<6; ++nt){
                bf16x8 bf = *(const bf16x8*)&Bs[(nt*16 + l16)*132 + ks*32 + quad*8];
                acc[ph*6+nt] = __builtin_amdgcn_mfma_f32_16x16x32_bf16(
                    af, bf, acc[ph*6+nt], 0, 0, 0);
            }
        }
    }

    float pb[12], gv[12], bv[12];
    #pragma unroll
    for (int nt=0; nt<12; ++nt){
        int col = nt*16 + l16;
        pb[nt] = pe_b[col]; gv[nt] = gg[col]; bv[nt] = bb[col];
    }
    #pragma unroll
    for (int r=0; r<4; ++r){
        int row = wave*16 + quad*4 + r;
        int pos = m0 + row;
        float sv[12], s1 = 0.f, s2 = 0.f;
        #pragma unroll
        for (int nt=0; nt<12; ++nt){
            float v = acc[nt][r] + pb[nt];
            sv[nt] = v; s1 += v; s2 += v*v;
        }
        #pragma unroll
        for (int off=1; off<16; off<<=1){
            s1 += __shfl_xor(s1, off); s2 += __shfl_xor(s2, off);
        }
        float mean = s1*(1.f/192.f);
        float rstd = rsqrtf(s2*(1.f/192.f) - mean*mean + 1e-5f);
        #pragma unroll
        for (int nt=0; nt<12; ++nt){
            int col = nt*16 + l16;
            e[(size_t)pos*CCH + col] = (sv[nt]-mean)*rstd*gv[nt] + bv[nt];
        }
    }
}

// ---------------- reconstruction via MFMA ----------------------------------
__global__ __launch_bounds__(256) void recon_mfma(
    const float* __restrict__ e, const unsigned short* __restrict__ rwt,
    const float* __restrict__ rec_b, float* __restrict__ out)
{
    __shared__ __align__(16) unsigned short As[64*196];
    __shared__ __align__(16) unsigned short Bs[64*196];
    int t = threadIdx.x;
    int wave = t>>6, lane = t&63, quad = lane>>4, l16 = lane&15;
    int m0 = blockIdx.x*64;

    #pragma unroll
    for (int it=0; it<12; ++it){
        int g = it*256 + t;
        int row = g/48, c4 = g - row*48;
        float4 v = *(const float4*)&e[(size_t)(m0+row)*CCH + c4*4];
        *(ushort4*)&As[row*196 + c4*4] = cvt4(v);
    }

    f32x4 acc[8] = {};
    #pragma unroll
    for (int ph = 0; ph < 2; ++ph){
        if (ph) __syncthreads();
        #pragma unroll
        for (int it=0; it<6; ++it){
            int g = it*256 + t;
            int row = g/24, c8 = g - row*24;
            const unsigned short* src = rwt + ((size_t)(ph*64+row))*192 + c8*8;
            uint4 u = *(const uint4*)src;
            unsigned short* dst = &Bs[row*196 + c8*8];
            *(uint2*)dst     = make_uint2(u.x, u.y);
            *(uint2*)(dst+4) = make_uint2(u.z, u.w);
        }
        __syncthreads();
        #pragma unroll
        for (int ks=0; ks<6; ++ks){
            bf16x8 af = *(const bf16x8*)&As[(wave*16 + l16)*196 + ks*32 + quad*8];
            #pragma unroll
            for (int nt=0; nt<4; ++nt){
                bf16x8 bf = *(const bf16x8*)&Bs[(nt*16 + l16)*196 + ks*32 + quad*8];
                acc[ph*4+nt] = __builtin_amdgcn_mfma_f32_16x16x32_bf16(
                    af, bf, acc[ph*4+nt], 0, 0, 0);
            }
        }
    }

    #pragma unroll
    for (int nt=0; nt<8; ++nt){
        int col = nt*16 + l16;
        int o = col>>5, i = (col>>4)&1, j = (col>>2)&3, k = col&3;
        float rb = rec_b[o];
        #pragma unroll
        for (int r=0; r<4; ++r){
            int pos = m0 + wave*16 + quad*4 + r;
            int w = pos&31, h=(pos>>5)&31, z=(pos>>10)&31, b=pos>>15;
            out[ (((size_t)(b*4+o)*64 + (z*2+i))*128 + (h*4+j))*128 + (w*4+k) ]
                = acc[nt][r] + rb;
        }
    }
}

// ---------------- LayerNorm -> bf16; window_mode gathers shifted rows ------
__global__ __launch_bounds__(192) void ln_kernel(
    const float* __restrict__ in, unsigned short* __restrict__ outp,
    const float* __restrict__ gg, const float* __restrict__ bb,
    int window_mode, int shifted, int row0)
{
    int tid = threadIdx.x;
    int r = blockIdx.x + row0;
    int src;
    if (window_mode){
        int wb = r>>7, tok = r&127;
        int b = wb>>8, nw = wb&255;
        int zs = (nw>>4)*2 + (tok>>6);
        int hs = ((nw>>2)&3)*8 + ((tok>>3)&7);
        int ws = (nw&3)*8 + (tok&7);
        int z,h,w;
        if (shifted){ z=(zs+1)&31; h=(hs+4)&31; w=(ws+4)&31; }
        else        { z=zs; h=hs; w=ws; }
        src = ((b*32+z)*32+h)*32+w;
    } else src = r;
    float val = in[(size_t)src*CCH + tid];
    float s = val, s2 = val*val;
    for (int off=32; off>=1; off>>=1){ s += __shfl_xor(s,off); s2 += __shfl_xor(s2,off); }
    __shared__ float red[2][3];
    if ((tid&63)==0){ red[0][tid>>6]=s; red[1][tid>>6]=s2; }
    __syncthreads();
    float sum = red[0][0]+red[0][1]+red[0][2];
    float sq  = red[1][0]+red[1][1]+red[1][2];
    float mean = sum*(1.f/192.f);
    float rstd = rsqrtf(sq*(1.f/192.f) - mean*mean + 1e-5f);
    outp[(size_t)blockIdx.x*CCH + tid] = f2bf((val-mean)*rstd*gg[tid] + bb[tid]);
}

// ---------------- bf16 MFMA GEMM: C = A * Bt^T + bias ----------------------
// MODE 1: gelu->bf16. 2: window-reverse residual add (fp32 e).
// MODE 3: fp32 += (global rows). 4: plain bf16 out.
// MODE 5: qkv split epilogue: n<384 -> Ch[m][384] row-major (Q|K);
//         n>=384 -> Vout[win][d=n-384][tok] transposed bf16.
template<int MODE>
__global__ __launch_bounds__(256) void gemm_mfma(
    const unsigned short* __restrict__ A, const unsigned short* __restrict__ Bt,
    const float* __restrict__ bias, void* __restrict__ Cout,
    unsigned short* __restrict__ Vout,
    int N, int K, int shifted, int row0)
{
    __shared__ __align__(16) unsigned short As[128*32];
    __shared__ __align__(16) unsigned short Bs[64*32];
    int t = threadIdx.x;
    int wave = t >> 6, lane = t & 63;
    int quad = lane >> 4, l16 = lane & 15;
    int m0 = blockIdx.y * 128, n0 = blockIdx.x * 64;

    f32x4 acc[2][4] = {};
    int ldrow = lane >> 2;
    int ldk   = (lane & 3) * 8;

    for (int k0 = 0; k0 < K; k0 += 32){
        #pragma unroll
        for (int s2 = 0; s2 < 2; ++s2){
            int s = wave*2 + s2;
            async16(A + (size_t)(m0 + s*16 + ldrow)*K + k0 + ldk, &As[s*512]);
        }
        async16(Bt + (size_t)(n0 + wave*16 + ldrow)*K + k0 + ldk, &Bs[wave*512]);
        __syncthreads();
        bf16x8 af[2], bfr[4];
        #pragma unroll
        for (int mt=0; mt<2; ++mt)
            af[mt] = *(const bf16x8*)&As[(wave*32 + mt*16 + l16)*32 + quad*8];
        #pragma unroll
        for (int nt=0; nt<4; ++nt)
            bfr[nt] = *(const bf16x8*)&Bs[(nt*16 + l16)*32 + quad*8];
        #pragma unroll
        for (int mt=0; mt<2; ++mt)
            #pragma unroll
            for (int nt=0; nt<4; ++nt)
                acc[mt][nt] = __builtin_amdgcn_mfma_f32_16x16x32_bf16(
                    af[mt], bfr[nt], acc[mt][nt], 0, 0, 0);
        __syncthreads();
    }

    float* Cf = (float*)Cout;
    unsigned short* Ch = (unsigned short*)Cout;
    #pragma unroll
    for (int mt=0; mt<2; ++mt){
        #pragma unroll
        for (int nt=0; nt<4; ++nt){
            int n = n0 + nt*16 + l16;
            if (MODE==5 && n0 + nt*16 >= 384){
                int d = n - 384;
                int win = m0 >> 7;
                int tok0 = wave*32 + mt*16 + quad*4;
                float bn = bias[n];
                ushort4 vv;
                vv.x = f2bf(acc[mt][nt][0]+bn); vv.y = f2bf(acc[mt][nt][1]+bn);
                vv.z = f2bf(acc[mt][nt][2]+bn); vv.w = f2bf(acc[mt][nt][3]+bn);
                *(ushort4*)&Vout[((size_t)win*192 + d)*128 + tok0] = vv;
                continue;
            }
            #pragma unroll
            for (int r=0; r<4; ++r){
                int m = m0 + wave*32 + mt*16 + quad*4 + r;
                float v = acc[mt][nt][r] + bias[n];
                if (MODE==5){
                    Ch[(size_t)m*384 + n] = f2bf(v);
                } else if (MODE==4){
                    Ch[(size_t)m*N + n] = f2bf(v);
                } else if (MODE==1){
                    v = 0.5f*v*(1.f + erff(v*0.70710678118654752f));
                    Ch[(size_t)m*N + n] = f2bf(v);
                } else if (MODE==3){
                    Cf[(size_t)(m+row0)*N + n] += v;
                } else {
                    int mg = m + row0;
                    int wb = mg>>7, tok = mg&127;
                    int b = wb>>8, nw = wb&255;
                    int zs = (nw>>4)*2 + (tok>>6);
                    int hs = ((nw>>2)&3)*8 + ((tok>>3)&7);
                    int ws = (nw&3)*8 + (tok&7);
                    int z,h,w;
                    if (shifted){ z=(zs+1)&31; h=(hs+4)&31; w=(ws+4)&31; }
                    else        { z=zs; h=hs; w=ws; }
                    Cf[(size_t)(((b*32+z)*32+h)*32+w)*CCH + n] += v;
                }
            }
        }
    }
}

// ---------------- MFMA attention, latency-restructured ---------------------
// LDS interleaved layouts (16 B per lane via global_load_lds):
//  K : off(tok,k) = (tok>>4)*512 + (k>>3)*128 + (tok&15)*8 + (k&7)   [4096]
//  Vt: off(d,tok) = (d>>4)*2048 + (tok>>5)*512 + ((tok>>3)&3)*128 + (d&15)*8 + (tok&7)
//  P : off(n,m)   = (n>>4)*2048 + (m>>5)*512 + ((m>>3)&3)*128 + (n&15)*8 + (m&7)
// bias_il precomputed in P layout; staged into Ps, overwritten in-place.
__global__ __launch_bounds__(256) void attn_mfma(
    const unsigned short* __restrict__ qk,     // [rows][384] Q|K bf16
    const unsigned short* __restrict__ vbuf,   // [win][192][128] bf16
    unsigned short* __restrict__ obuf,         // [rows][192] bf16
    const unsigned short* __restrict__ bias_layer, // + head*16384
    int shifted, int wb0)
{
    __shared__ __align__(16) unsigned short Ks[4096];
    __shared__ __align__(16) unsigned short Vt[4096];
    __shared__ __align__(16) unsigned short Ps[16384];
    __shared__ float linv[128];
    __shared__ int grp[128];

    int t = threadIdx.x;
    int wave = t >> 6, lane = t & 63;
    int quad = lane >> 4, l16 = lane & 15;
    int wb = blockIdx.x / HEADS;
    int head = blockIdx.x % HEADS;
    int nw = (wb + wb0) & 255;

    const unsigned short* qkw = qk + (size_t)wb*128*384;

    // Q fragments direct from global (issued before barrier)
    bf16x8 af[2];
    #pragma unroll
    for (int mt=0; mt<2; ++mt)
        af[mt] = *(const bf16x8*)(qkw + (size_t)(wave*32 + mt*16 + l16)*384 + head*32 + quad*8);

    // async stage: K (2/wave), Vt (2/wave), bias (8/wave)
    {
        int chunk = lane >> 4, low = lane & 15;
        #pragma unroll
        for (int i=0; i<2; ++i){
            int j = wave*2 + i;   // token group of 16
            async16(qkw + (size_t)(j*16 + low)*384 + 192 + head*32 + chunk*8, &Ks[j*512]);
        }
        const unsigned short* vb = vbuf + ((size_t)wb*192 + head*32)*128;
        #pragma unroll
        for (int i=0; i<2; ++i){
            int j = wave*2 + i; int dgrp = j>>2, tg = j&3;
            async16(vb + (size_t)(dgrp*16 + low)*128 + tg*32 + chunk*8, &Vt[j*512]);
        }
        const unsigned short* bsrc = bias_layer + (size_t)head*16384;
        #pragma unroll
        for (int i=0; i<8; ++i){
            int j = wave*8 + i;
            async16(bsrc + j*512 + lane*8, &Ps[j*512]);
        }
    }
    if (t < 128 && shifted){
        int zs = (nw>>4)*2 + (t>>6);
        int hs = ((nw>>2)&3)*8 + ((t>>3)&7);
        int ws = (nw&3)*8 + (t&7);
        grp[t] = zone_z(zs)*9 + zone_hw(hs)*3 + zone_hw(ws);
    }
    __syncthreads();

    // ---- S = Q K^T ----
    f32x4 sacc[2][8] = {};
    #pragma unroll
    for (int nt=0; nt<8; ++nt){
        bf16x8 bfr = *(const bf16x8*)&Ks[nt*512 + quad*128 + l16*8];
        sacc[0][nt] = __builtin_amdgcn_mfma_f32_16x16x32_bf16(af[0], bfr, sacc[0][nt], 0,0,0);
        sacc[1][nt] = __builtin_amdgcn_mfma_f32_16x16x32_bf16(af[1], bfr, sacc[1][nt], 0,0,0);
    }

    // ---- softmax: bias from Ps (LDS), overwrite with P in place ----
    const float scale = 0.17677669529663689f;
    #pragma unroll
    for (int mt=0; mt<2; ++mt){
        #pragma unroll
        for (int r=0; r<4; ++r){
            int row = wave*32 + mt*16 + quad*4 + r;
            int rbase = (wave*2+mt)*2048 + (quad*4+r)*8;
            int myg = shifted ? grp[row] : 0;
            float sv[8]; int offv[8];
            float mloc = -1e30f;
            #pragma unroll
            for (int nt=0; nt<8; ++nt){
                int off = rbase + (nt>>1)*512 + (((nt&1)<<1) + (l16>>3))*128 + (l16&7);
                offv[nt] = off;
                float s = sacc[mt][nt][r]*scale + bf2f(Ps[off]);
                if (shifted && grp[nt*16+l16] != myg) s -= 100.f;
                sv[nt] = s;
                mloc = fmaxf(mloc, s);
            }
            #pragma unroll
            for (int off=1; off<16; off<<=1) mloc = fmaxf(mloc, __shfl_xor(mloc, off));
            float lloc = 0.f;
            #pragma unroll
            for (int nt=0; nt<8; ++nt){
                float p = __expf(sv[nt]-mloc);
                sv[nt] = p; lloc += p;
            }
            #pragma unroll
            for (int off=1; off<16; off<<=1) lloc += __shfl_xor(lloc, off);
            #pragma unroll
            for (int nt=0; nt<8; ++nt)
                Ps[offv[nt]] = f2bf(sv[nt]);
            if (l16==0) linv[row] = 1.f/lloc;
        }
    }
    // no barrier: each wave reads only its own Ps rows / linv entries below

    // ---- O^T = V^T P^T ----
    f32x4 oacc[2][2] = {};
    #pragma unroll
    for (int ks=0; ks<4; ++ks){
        bf16x8 av0 = *(const bf16x8*)&Vt[         ks*512 + quad*128 + l16*8];
        bf16x8 av1 = *(const bf16x8*)&Vt[ 2048 +  ks*512 + quad*128 + l16*8];
        bf16x8 pf0 = *(const bf16x8*)&Ps[(wave*2+0)*2048 + ks*512 + quad*128 + l16*8];
        bf16x8 pf1 = *(const bf16x8*)&Ps[(wave*2+1)*2048 + ks*512 + quad*128 + l16*8];
        oacc[0][0] = __builtin_amdgcn_mfma_f32_16x16x32_bf16(av0, pf0, oacc[0][0], 0,0,0);
        oacc[0][1] = __builtin_amdgcn_mfma_f32_16x16x32_bf16(av1, pf0, oacc[0][1], 0,0,0);
        oacc[1][0] = __builtin_amdgcn_mfma_f32_16x16x32_bf16(av0, pf1, oacc[1][0], 0,0,0);
        oacc[1][1] = __builtin_amdgcn_mfma_f32_16x16x32_bf16(av1, pf1, oacc[1][1], 0,0,0);
    }

    #pragma unroll
    for (int mt=0; mt<2; ++mt){
        int token = wave*32 + mt*16 + l16;
        float inv = linv[token];
        unsigned short* dst = obuf + (size_t)(wb*128+token)*CCH + head*32;
        #pragma unroll
        for (int dt=0; dt<2; ++dt){
            ushort4 v4;
            v4.x = f2bf(oacc[mt][dt][0]*inv);
            v4.y = f2bf(oacc[mt][dt][1]*inv);
            v4.z = f2bf(oacc[mt][dt][2]*inv);
            v4.w = f2bf(oacc[mt][dt][3]*inv);
            *(ushort4*)&dst[dt*16 + quad*4] = v4;
        }
    }
}

extern "C" void kernel_launch(void* const* d_in, const int* in_sizes, int n_in,
                              void* d_out, int out_size, void* d_ws, size_t ws_size,
                              hipStream_t stream) {
    const float* x       = (const float*)d_in[0];
    const float* pe_w    = (const float*)d_in[1];
    const float* pe_b    = (const float*)d_in[2];
    const float* pe_ln_g = (const float*)d_in[3];
    const float* pe_ln_b = (const float*)d_in[4];
    const float* ln1_g   = (const float*)d_in[5];
    const float* ln1_b   = (const float*)d_in[6];
    const float* qkv_w   = (const float*)d_in[7];
    const float* qkv_b   = (const float*)d_in[8];
    const float* proj_w  = (const float*)d_in[9];
    const float* proj_b  = (const float*)d_in[10];
    const float* rpb     = (const float*)d_in[11];
    const float* ln2_g   = (const float*)d_in[12];
    const float* ln2_b   = (const float*)d_in[13];
    const float* fc1_w   = (const float*)d_in[14];
    const float* fc1_b   = (const float*)d_in[15];
    const float* fc2_w   = (const float*)d_in[16];
    const float* fc2_b   = (const float*)d_in[17];
    const float* rec_w   = (const float*)d_in[18];
    const float* rec_b   = (const float*)d_in[19];
    float* out = (float*)d_out;
    char* wsb = (char*)d_ws;

    float*          e        = (float*)wsb;
    unsigned short* bias_il  = (unsigned short*)(wsb + 50331648);
    unsigned short* wt       = (unsigned short*)(wsb + 51904512);
    unsigned short* pwb      = wt + 1769472;
    unsigned short* rwt      = wt + 1794048;
    char*           stage    = wsb + 55541760;
    size_t scap = ws_size > 55541760 ? ws_size - 55541760 : 0;

    int WCH = 512;
    while (WCH > 16 && (size_t)WCH*128*1920 > scap) WCH >>= 1;
    int RCH = 65536;
    while (RCH > 2048 && (size_t)RCH*1920 > scap) RCH >>= 1;

    for (int d = 0; d < 4; ++d){
        unsigned short* wl = wt + (size_t)d*442368;
        wt_convert<<<(110592+255)/256, 256, 0, stream>>>(qkv_w  + (size_t)d*110592, wl,          192, 576);
        wt_convert<<<( 36864+255)/256, 256, 0, stream>>>(proj_w + (size_t)d* 36864, wl + 110592, 192, 192);
        wt_convert<<<(147456+255)/256, 256, 0, stream>>>(fc1_w  + (size_t)d*147456, wl + 147456, 192, 768);
        wt_convert<<<(147456+255)/256, 256, 0, stream>>>(fc2_w  + (size_t)d*147456, wl + 294912, 768, 192);
    }
    pe_conv<<<96, 256, 0, stream>>>(pe_w, pwb, 24576);
    wt_convert<<<96, 256, 0, stream>>>(rec_w, rwt, 192, 128);

    bias_precompute<<<24, 128, 0, stream>>>(rpb, bias_il);
    patch_embed_mfma<<<1024, 256, 0, stream>>>(x, pwb, pe_b, pe_ln_g, pe_ln_b, e);

    for (int d = 0; d < 4; ++d){
        int sh = d & 1;
        unsigned short* wl = wt + (size_t)d*442368;
        for (int w0 = 0; w0 < 512; w0 += WCH){
            int rows = WCH*128;
            unsigned short* bufc = (unsigned short*)stage;                        // [rows][192]
            unsigned short* qkc  = (unsigned short*)(stage + (size_t)rows*384);   // [rows][384]
            unsigned short* vc   = (unsigned short*)(stage + (size_t)rows*1152);  // [WCH][192][128]
            unsigned short* oc   = (unsigned short*)(stage + (size_t)rows*1536);  // [rows][192]
            ln_kernel<<<rows, 192, 0, stream>>>(
                e, bufc, ln1_g + d*CCH, ln1_b + d*CCH, 1, sh, w0*128);
            gemm_mfma<5><<<dim3(9, rows/128), 256, 0, stream>>>(
                bufc, wl, qkv_b + d*3*CCH, qkc, vc, 576, 192, 0, 0);
            attn_mfma<<<WCH*HEADS, 256, 0, stream>>>(
                qkc, vc, oc, bias_il + (size_t)d*HEADS*16384, sh, w0);
            gemm_mfma<2><<<dim3(3, rows/128), 256, 0, stream>>>(
                oc, wl + 110592, proj_b + d*CCH, e, nullptr, 192, 192, sh, w0*128);
        }
        for (int r0 = 0; r0 < 65536; r0 += RCH){
            unsigned short* lnc = (unsigned short*)stage;
            unsigned short* hc  = (unsigned short*)(stage + (size_t)RCH*384);
            ln_kernel<<<RCH, 192, 0, stream>>>(
                e, lnc, ln2_g + d*CCH, ln2_b + d*CCH, 0, 0, r0);
            gemm_mfma<1><<<dim3(12, RCH/128), 256, 0, stream>>>(
                lnc, wl + 147456, fc1_b + d*4*CCH, hc, nullptr, 768, 192, 0, 0);
            gemm_mfma<3><<<dim3(3, RCH/128), 256, 0, stream>>>(
                hc, wl + 294912, fc2_b + d*CCH, e, nullptr, 192, 768, 0, r0);
        }
    }
    recon_mfma<<<1024, 256, 0, stream>>>(e, rwt, rec_b, out);
}

// Round 7
// 1443.775 us; speedup vs baseline: 3.5609x; 1.0375x over previous
//
#include <hip/hip_runtime.h>
#include <math.h>

// SwinDecoder on MI355X. Round 7: fused MLP megakernel (ln2+fc1+gelu+fc2+
// residual, h stays in LDS). Attention path unchanged from R6.
// ws layout (bytes):
//   e        : 0          .. 50,331,648   fp32 [65536][192]
//   bias_il  : 50,331,648 .. 51,118,080   bf16 interleaved [4][6][16384]
//   wt       : 51,904,512 .. 55,541,760   bf16 weights (4 layers + pe + rec)
//   stage    : 55,541,760 .. (attention chunk only; 1920 B/row)

#define CCH 192
#define HEADS 6

typedef __attribute__((ext_vector_type(8))) short bf16x8;
typedef __attribute__((ext_vector_type(4))) float f32x4;

__device__ __forceinline__ unsigned short f2bf(float f){
    union { float f; unsigned int u; } x; x.f = f;
    unsigned int r = (x.u + 0x7fffu + ((x.u >> 16) & 1u)) >> 16;
    return (unsigned short)r;
}
__device__ __forceinline__ float bf2f(unsigned short h){
    union { unsigned int u; float f; } x; x.u = ((unsigned int)h)<<16;
    return x.f;
}

__device__ __forceinline__ void async16(const void* g, void* l){
    __builtin_amdgcn_global_load_lds(
        (const __attribute__((address_space(1))) void*)g,
        (__attribute__((address_space(3))) void*)l, 16, 0, 0);
}

__device__ __forceinline__ ushort4 cvt4(float4 v){
    ushort4 r; r.x=f2bf(v.x); r.y=f2bf(v.y); r.z=f2bf(v.z); r.w=f2bf(v.w);
    return r;
}

__device__ __forceinline__ int zone_z(int z){ return z<30?0:(z<31?1:2); }
__device__ __forceinline__ int zone_hw(int h){ return h<24?0:(h<28?1:2); }

// ---------------- weight convert+transpose: w[K][N] fp32 -> wt[N][K] bf16 --
__global__ void wt_convert(const float* __restrict__ w, unsigned short* __restrict__ wt,
                           int K, int N)
{
    int idx = blockIdx.x*256 + threadIdx.x;
    if (idx >= K*N) return;
    int n = idx / K, k = idx - n*K;
    wt[idx] = f2bf(w[(size_t)k*N + n]);
}

// ---------------- plain fp32 -> bf16 convert -------------------------------
__global__ void pe_conv(const float* __restrict__ w, unsigned short* __restrict__ o, int n)
{
    int i = blockIdx.x*256 + threadIdx.x;
    if (i < n) o[i] = f2bf(w[i]);
}

// ---- rel-pos bias -> bf16 in MFMA-interleaved layout ----------------------
__global__ void bias_precompute(const float* __restrict__ rpb,
                                unsigned short* __restrict__ bias_il)
{
    int d = blockIdx.x / HEADS, head = blockIdx.x % HEADS;
    int n = threadIdx.x;
    int i1 = n>>6, j1 = (n>>3)&7, k1 = n&7;
    const float* rp = rpb + d*675*HEADS;
    unsigned short* out = bias_il + (size_t)blockIdx.x*16384;
    int rbase = (n>>4)*2048 + (n&15)*8;
    for (int m = 0; m < 128; ++m){
        int i2 = m>>6, j2 = (m>>3)&7, k2 = m&7;
        int idx = (i1-i2+1)*225 + (j1-j2+7)*15 + (k1-k2+7);
        int off = rbase + (m>>5)*512 + ((m>>3)&3)*128 + (m&7);
        out[off] = f2bf(rp[idx*HEADS + head]);
    }
}

// ---------------- patch embed via MFMA, LN fused in epilogue ---------------
__global__ __launch_bounds__(256) void patch_embed_mfma(
    const float* __restrict__ x, const unsigned short* __restrict__ pwb,
    const float* __restrict__ pe_b, const float* __restrict__ gg,
    const float* __restrict__ bb, float* __restrict__ e)
{
    __shared__ __align__(16) unsigned short As[64*132];
    __shared__ __align__(16) unsigned short Bs[96*132];
    int t = threadIdx.x;
    int wave = t>>6, lane = t&63, quad = lane>>4, l16 = lane&15;
    int m0 = blockIdx.x*64;

    {
        int row = t & 63, cg = (t>>6)*8;
        int pos = m0 + row;
        int w = pos&31, h=(pos>>5)&31, z=(pos>>10)&31, b=pos>>15;
        #pragma unroll
        for (int cc=0; cc<8; ++cc){
            int chunk = cg + cc;
            int c = chunk>>3, i=(chunk>>2)&1, j=chunk&3;
            float4 v = *(const float4*)&x[ (((size_t)(b*4+c)*64 + (z*2+i))*128 + (h*4+j))*128 + w*4 ];
            *(ushort4*)&As[row*132 + chunk*4] = cvt4(v);
        }
    }

    f32x4 acc[12] = {};
    #pragma unroll
    for (int ph = 0; ph < 2; ++ph){
        if (ph) __syncthreads();
        #pragma unroll
        for (int it=0; it<6; ++it){
            int g = it*256 + t;
            int row = g >> 4, c8 = g & 15;
            const unsigned short* src = pwb + ((size_t)(ph*96+row))*128 + c8*8;
            uint4 u = *(const uint4*)src;
            unsigned short* dst = &Bs[row*132 + c8*8];
            *(uint2*)dst       = make_uint2(u.x, u.y);
            *(uint2*)(dst+4)   = make_uint2(u.z, u.w);
        }
        __syncthreads();
        #pragma unroll
        for (int ks=0; ks<4; ++ks){
            bf16x8 af = *(const bf16x8*)&As[(wave*16 + l16)*132 + ks*32 + quad*8];
            #pragma unroll
            for (int nt=0; nt<6; ++nt){
                bf16x8 bf = *(const bf16x8*)&Bs[(nt*16 + l16)*132 + ks*32 + quad*8];
                acc[ph*6+nt] = __builtin_amdgcn_mfma_f32_16x16x32_bf16(
                    af, bf, acc[ph*6+nt], 0, 0, 0);
            }
        }
    }

    float pb[12], gv[12], bv[12];
    #pragma unroll
    for (int nt=0; nt<12; ++nt){
        int col = nt*16 + l16;
        pb[nt] = pe_b[col]; gv[nt] = gg[col]; bv[nt] = bb[col];
    }
    #pragma unroll
    for (int r=0; r<4; ++r){
        int row = wave*16 + quad*4 + r;
        int pos = m0 + row;
        float sv[12], s1 = 0.f, s2 = 0.f;
        #pragma unroll
        for (int nt=0; nt<12; ++nt){
            float v = acc[nt][r] + pb[nt];
            sv[nt] = v; s1 += v; s2 += v*v;
        }
        #pragma unroll
        for (int off=1; off<16; off<<=1){
            s1 += __shfl_xor(s1, off); s2 += __shfl_xor(s2, off);
        }
        float mean = s1*(1.f/192.f);
        float rstd = rsqrtf(s2*(1.f/192.f) - mean*mean + 1e-5f);
        #pragma unroll
        for (int nt=0; nt<12; ++nt){
            int col = nt*16 + l16;
            e[(size_t)pos*CCH + col] = (sv[nt]-mean)*rstd*gv[nt] + bv[nt];
        }
    }
}

// ---------------- reconstruction via MFMA ----------------------------------
__global__ __launch_bounds__(256) void recon_mfma(
    const float* __restrict__ e, const unsigned short* __restrict__ rwt,
    const float* __restrict__ rec_b, float* __restrict__ out)
{
    __shared__ __align__(16) unsigned short As[64*196];
    __shared__ __align__(16) unsigned short Bs[64*196];
    int t = threadIdx.x;
    int wave = t>>6, lane = t&63, quad = lane>>4, l16 = lane&15;
    int m0 = blockIdx.x*64;

    #pragma unroll
    for (int it=0; it<12; ++it){
        int g = it*256 + t;
        int row = g/48, c4 = g - row*48;
        float4 v = *(const float4*)&e[(size_t)(m0+row)*CCH + c4*4];
        *(ushort4*)&As[row*196 + c4*4] = cvt4(v);
    }

    f32x4 acc[8] = {};
    #pragma unroll
    for (int ph = 0; ph < 2; ++ph){
        if (ph) __syncthreads();
        #pragma unroll
        for (int it=0; it<6; ++it){
            int g = it*256 + t;
            int row = g/24, c8 = g - row*24;
            const unsigned short* src = rwt + ((size_t)(ph*64+row))*192 + c8*8;
            uint4 u = *(const uint4*)src;
            unsigned short* dst = &Bs[row*196 + c8*8];
            *(uint2*)dst     = make_uint2(u.x, u.y);
            *(uint2*)(dst+4) = make_uint2(u.z, u.w);
        }
        __syncthreads();
        #pragma unroll
        for (int ks=0; ks<6; ++ks){
            bf16x8 af = *(const bf16x8*)&As[(wave*16 + l16)*196 + ks*32 + quad*8];
            #pragma unroll
            for (int nt=0; nt<4; ++nt){
                bf16x8 bf = *(const bf16x8*)&Bs[(nt*16 + l16)*196 + ks*32 + quad*8];
                acc[ph*4+nt] = __builtin_amdgcn_mfma_f32_16x16x32_bf16(
                    af, bf, acc[ph*4+nt], 0, 0, 0);
            }
        }
    }

    #pragma unroll
    for (int nt=0; nt<8; ++nt){
        int col = nt*16 + l16;
        int o = col>>5, i = (col>>4)&1, j = (col>>2)&3, k = col&3;
        float rb = rec_b[o];
        #pragma unroll
        for (int r=0; r<4; ++r){
            int pos = m0 + wave*16 + quad*4 + r;
            int w = pos&31, h=(pos>>5)&31, z=(pos>>10)&31, b=pos>>15;
            out[ (((size_t)(b*4+o)*64 + (z*2+i))*128 + (h*4+j))*128 + (w*4+k) ]
                = acc[nt][r] + rb;
        }
    }
}

// ---------------- LayerNorm -> bf16; window gather (ln1 path) --------------
__global__ __launch_bounds__(192) void ln_kernel(
    const float* __restrict__ in, unsigned short* __restrict__ outp,
    const float* __restrict__ gg, const float* __restrict__ bb,
    int shifted, int row0)
{
    int tid = threadIdx.x;
    int r = blockIdx.x + row0;
    int wb = r>>7, tok = r&127;
    int b = wb>>8, nw = wb&255;
    int zs = (nw>>4)*2 + (tok>>6);
    int hs = ((nw>>2)&3)*8 + ((tok>>3)&7);
    int ws = (nw&3)*8 + (tok&7);
    int z,h,w;
    if (shifted){ z=(zs+1)&31; h=(hs+4)&31; w=(ws+4)&31; }
    else        { z=zs; h=hs; w=ws; }
    int src = ((b*32+z)*32+h)*32+w;
    float val = in[(size_t)src*CCH + tid];
    float s = val, s2 = val*val;
    for (int off=32; off>=1; off>>=1){ s += __shfl_xor(s,off); s2 += __shfl_xor(s2,off); }
    __shared__ float red[2][3];
    if ((tid&63)==0){ red[0][tid>>6]=s; red[1][tid>>6]=s2; }
    __syncthreads();
    float sum = red[0][0]+red[0][1]+red[0][2];
    float sq  = red[1][0]+red[1][1]+red[1][2];
    float mean = sum*(1.f/192.f);
    float rstd = rsqrtf(sq*(1.f/192.f) - mean*mean + 1e-5f);
    outp[(size_t)blockIdx.x*CCH + tid] = f2bf((val-mean)*rstd*gg[tid] + bb[tid]);
}

// ---------------- bf16 MFMA GEMM ------------------------------------------
// MODE 2: window-reverse residual add (fp32 e).
// MODE 5: qkv split: n<384 -> Ch[m][384] (Q|K); n>=384 -> Vout[win][d][tok].
template<int MODE>
__global__ __launch_bounds__(256) void gemm_mfma(
    const unsigned short* __restrict__ A, const unsigned short* __restrict__ Bt,
    const float* __restrict__ bias, void* __restrict__ Cout,
    unsigned short* __restrict__ Vout,
    int N, int K, int shifted, int row0)
{
    __shared__ __align__(16) unsigned short As[128*32];
    __shared__ __align__(16) unsigned short Bs[64*32];
    int t = threadIdx.x;
    int wave = t >> 6, lane = t & 63;
    int quad = lane >> 4, l16 = lane & 15;
    int m0 = blockIdx.y * 128, n0 = blockIdx.x * 64;

    f32x4 acc[2][4] = {};
    int ldrow = lane >> 2;
    int ldk   = (lane & 3) * 8;

    for (int k0 = 0; k0 < K; k0 += 32){
        #pragma unroll
        for (int s2 = 0; s2 < 2; ++s2){
            int s = wave*2 + s2;
            async16(A + (size_t)(m0 + s*16 + ldrow)*K + k0 + ldk, &As[s*512]);
        }
        async16(Bt + (size_t)(n0 + wave*16 + ldrow)*K + k0 + ldk, &Bs[wave*512]);
        __syncthreads();
        bf16x8 af[2], bfr[4];
        #pragma unroll
        for (int mt=0; mt<2; ++mt)
            af[mt] = *(const bf16x8*)&As[(wave*32 + mt*16 + l16)*32 + quad*8];
        #pragma unroll
        for (int nt=0; nt<4; ++nt)
            bfr[nt] = *(const bf16x8*)&Bs[(nt*16 + l16)*32 + quad*8];
        #pragma unroll
        for (int mt=0; mt<2; ++mt)
            #pragma unroll
            for (int nt=0; nt<4; ++nt)
                acc[mt][nt] = __builtin_amdgcn_mfma_f32_16x16x32_bf16(
                    af[mt], bfr[nt], acc[mt][nt], 0, 0, 0);
        __syncthreads();
    }

    float* Cf = (float*)Cout;
    unsigned short* Ch = (unsigned short*)Cout;
    #pragma unroll
    for (int mt=0; mt<2; ++mt){
        #pragma unroll
        for (int nt=0; nt<4; ++nt){
            int n = n0 + nt*16 + l16;
            if (MODE==5 && n0 + nt*16 >= 384){
                int d = n - 384;
                int win = m0 >> 7;
                int tok0 = wave*32 + mt*16 + quad*4;
                float bn = bias[n];
                ushort4 vv;
                vv.x = f2bf(acc[mt][nt][0]+bn); vv.y = f2bf(acc[mt][nt][1]+bn);
                vv.z = f2bf(acc[mt][nt][2]+bn); vv.w = f2bf(acc[mt][nt][3]+bn);
                *(ushort4*)&Vout[((size_t)win*192 + d)*128 + tok0] = vv;
                continue;
            }
            #pragma unroll
            for (int r=0; r<4; ++r){
                int m = m0 + wave*32 + mt*16 + quad*4 + r;
                float v = acc[mt][nt][r] + bias[n];
                if (MODE==5){
                    Ch[(size_t)m*384 + n] = f2bf(v);
                } else {
                    int mg = m + row0;
                    int wb = mg>>7, tok = mg&127;
                    int b = wb>>8, nw = wb&255;
                    int zs = (nw>>4)*2 + (tok>>6);
                    int hs = ((nw>>2)&3)*8 + ((tok>>3)&7);
                    int ws = (nw&3)*8 + (tok&7);
                    int z,h,w;
                    if (shifted){ z=(zs+1)&31; h=(hs+4)&31; w=(ws+4)&31; }
                    else        { z=zs; h=hs; w=ws; }
                    Cf[(size_t)(((b*32+z)*32+h)*32+w)*CCH + n] += v;
                }
            }
        }
    }
}

// ---------------- fused MLP: ln2 + fc1 + gelu + fc2 + residual -------------
// 64 rows/block, 4 waves, wave-private 16 rows. h lives in LDS only.
// A/H layouts per wave region (3072 shorts): off(r,k)=(k>>3)*128 + r*8 + (k&7).
// Bs: 12 n-groups x 64 k per stage: off = j*1024 + (kc)*128 + n16*8.
__global__ __launch_bounds__(256) void mlp_fused(
    float* __restrict__ e,
    const unsigned short* __restrict__ w1t, const float* __restrict__ b1,
    const unsigned short* __restrict__ w2t, const float* __restrict__ b2,
    const float* __restrict__ g2, const float* __restrict__ be2)
{
    __shared__ __align__(16) unsigned short As[64*192];
    __shared__ __align__(16) unsigned short Hs[64*192];
    __shared__ __align__(16) unsigned short Bs[192*64];
    int t = threadIdx.x;
    int wave = t>>6, lane = t&63, quad = lane>>4, l16 = lane&15;
    int m0 = blockIdx.x*64;
    unsigned short* Aw = As + wave*3072;
    unsigned short* Hw = Hs + wave*3072;

    // ---- LN2 over the wave's 16 rows (lane-strided, 64-lane butterfly) ----
    float g0 = g2[lane],  gA = g2[lane+64],  gB = g2[lane+128];
    float c0 = be2[lane], cA = be2[lane+64], cB = be2[lane+128];
    for (int rr=0; rr<16; ++rr){
        const float* row = e + (size_t)(m0 + wave*16 + rr)*CCH;
        float v0 = row[lane], v1 = row[lane+64], v2 = row[lane+128];
        float s = v0+v1+v2, q = v0*v0+v1*v1+v2*v2;
        #pragma unroll
        for (int o=1;o<64;o<<=1){ s += __shfl_xor(s,o); q += __shfl_xor(q,o); }
        float mean = s*(1.f/192.f);
        float rstd = rsqrtf(q*(1.f/192.f) - mean*mean + 1e-5f);
        int lo = lane>>3, sub = lane&7;
        Aw[(lo     )*128 + rr*8 + sub] = f2bf((v0-mean)*rstd*g0 + c0);
        Aw[(lo +  8)*128 + rr*8 + sub] = f2bf((v1-mean)*rstd*gA + cA);
        Aw[(lo + 16)*128 + rr*8 + sub] = f2bf((v2-mean)*rstd*gB + cB);
    }

    f32x4 acc2[12] = {};
    int tt = t & 127;
    int jadd = t >> 7;          // staging: upper half of block does odd groups
    int n16 = tt & 15, kc = tt >> 4;

    for (int c = 0; c < 4; ++c){
        // ---- fc1 chunk: h[.,c*192..+192) = A @ w1t[c-rows]^T ----
        f32x4 acc1[12] = {};
        for (int ks = 0; ks < 3; ++ks){
            __syncthreads();            // prior Bs readers done
            #pragma unroll
            for (int i=0; i<6; ++i){
                int j = i*2 + jadd;
                async16(w1t + (size_t)(c*192 + j*16 + n16)*192 + ks*64 + kc*8,
                        &Bs[j*1024 + kc*128 + n16*8]);
            }
            __syncthreads();            // staging visible
            #pragma unroll
            for (int half=0; half<2; ++half){
                bf16x8 af = *(const bf16x8*)&Aw[(ks*8 + half*4 + quad)*128 + l16*8];
                #pragma unroll
                for (int nt=0; nt<12; ++nt){
                    bf16x8 bf = *(const bf16x8*)&Bs[nt*1024 + (half*4+quad)*128 + l16*8];
                    acc1[nt] = __builtin_amdgcn_mfma_f32_16x16x32_bf16(
                        af, bf, acc1[nt], 0, 0, 0);
                }
            }
        }
        // ---- gelu + write h chunk to wave-private LDS ----
        #pragma unroll
        for (int nt=0; nt<12; ++nt){
            float bias1 = b1[c*192 + nt*16 + l16];
            int ko = nt*2 + (l16>>3), sub = l16&7;
            #pragma unroll
            for (int r=0; r<4; ++r){
                float v = acc1[nt][r] + bias1;
                v = 0.5f*v*(1.f + erff(v*0.70710678118654752f));
                Hw[ko*128 + (quad*4+r)*8 + sub] = f2bf(v);
            }
        }
        // ---- fc2 partial: acc2 += h_chunk @ w2t[:, c-range]^T ----
        for (int ks = 0; ks < 3; ++ks){
            __syncthreads();
            #pragma unroll
            for (int i=0; i<6; ++i){
                int j = i*2 + jadd;
                async16(w2t + (size_t)(j*16 + n16)*768 + c*192 + ks*64 + kc*8,
                        &Bs[j*1024 + kc*128 + n16*8]);
            }
            __syncthreads();
            #pragma unroll
            for (int half=0; half<2; ++half){
                bf16x8 af = *(const bf16x8*)&Hw[(ks*8 + half*4 + quad)*128 + l16*8];
                #pragma unroll
                for (int nt=0; nt<12; ++nt){
                    bf16x8 bf = *(const bf16x8*)&Bs[nt*1024 + (half*4+quad)*128 + l16*8];
                    acc2[nt] = __builtin_amdgcn_mfma_f32_16x16x32_bf16(
                        af, bf, acc2[nt], 0, 0, 0);
                }
            }
        }
    }

    // ---- epilogue: e += fc2 out + bias (residual re-read, L2-hot) ----
    #pragma unroll
    for (int nt=0; nt<12; ++nt){
        int n = nt*16 + l16;
        float bias2 = b2[n];
        #pragma unroll
        for (int r=0; r<4; ++r){
            size_t idx = (size_t)(m0 + wave*16 + quad*4 + r)*CCH + n;
            e[idx] += acc2[nt][r] + bias2;
        }
    }
}

// ---------------- MFMA attention (unchanged from R6) -----------------------
__global__ __launch_bounds__(256) void attn_mfma(
    const unsigned short* __restrict__ qk,
    const unsigned short* __restrict__ vbuf,
    unsigned short* __restrict__ obuf,
    const unsigned short* __restrict__ bias_layer,
    int shifted, int wb0)
{
    __shared__ __align__(16) unsigned short Ks[4096];
    __shared__ __align__(16) unsigned short Vt[4096];
    __shared__ __align__(16) unsigned short Ps[16384];
    __shared__ float linv[128];
    __shared__ int grp[128];

    int t = threadIdx.x;
    int wave = t >> 6, lane = t & 63;
    int quad = lane >> 4, l16 = lane & 15;
    int wb = blockIdx.x / HEADS;
    int head = blockIdx.x % HEADS;
    int nw = (wb + wb0) & 255;

    const unsigned short* qkw = qk + (size_t)wb*128*384;

    bf16x8 af[2];
    #pragma unroll
    for (int mt=0; mt<2; ++mt)
        af[mt] = *(const bf16x8*)(qkw + (size_t)(wave*32 + mt*16 + l16)*384 + head*32 + quad*8);

    {
        int chunk = lane >> 4, low = lane & 15;
        #pragma unroll
        for (int i=0; i<2; ++i){
            int j = wave*2 + i;
            async16(qkw + (size_t)(j*16 + low)*384 + 192 + head*32 + chunk*8, &Ks[j*512]);
        }
        const unsigned short* vb = vbuf + ((size_t)wb*192 + head*32)*128;
        #pragma unroll
        for (int i=0; i<2; ++i){
            int j = wave*2 + i; int dgrp = j>>2, tg = j&3;
            async16(vb + (size_t)(dgrp*16 + low)*128 + tg*32 + chunk*8, &Vt[j*512]);
        }
        const unsigned short* bsrc = bias_layer + (size_t)head*16384;
        #pragma unroll
        for (int i=0; i<8; ++i){
            int j = wave*8 + i;
            async16(bsrc + j*512 + lane*8, &Ps[j*512]);
        }
    }
    if (t < 128 && shifted){
        int zs = (nw>>4)*2 + (t>>6);
        int hs = ((nw>>2)&3)*8 + ((t>>3)&7);
        int ws = (nw&3)*8 + (t&7);
        grp[t] = zone_z(zs)*9 + zone_hw(hs)*3 + zone_hw(ws);
    }
    __syncthreads();

    f32x4 sacc[2][8] = {};
    #pragma unroll
    for (int nt=0; nt<8; ++nt){
        bf16x8 bfr = *(const bf16x8*)&Ks[nt*512 + quad*128 + l16*8];
        sacc[0][nt] = __builtin_amdgcn_mfma_f32_16x16x32_bf16(af[0], bfr, sacc[0][nt], 0,0,0);
        sacc[1][nt] = __builtin_amdgcn_mfma_f32_16x16x32_bf16(af[1], bfr, sacc[1][nt], 0,0,0);
    }

    const float scale = 0.17677669529663689f;
    #pragma unroll
    for (int mt=0; mt<2; ++mt){
        #pragma unroll
        for (int r=0; r<4; ++r){
            int row = wave*32 + mt*16 + quad*4 + r;
            int rbase = (wave*2+mt)*2048 + (quad*4+r)*8;
            int myg = shifted ? grp[row] : 0;
            float sv[8]; int offv[8];
            float mloc = -1e30f;
            #pragma unroll
            for (int nt=0; nt<8; ++nt){
                int off = rbase + (nt>>1)*512 + (((nt&1)<<1) + (l16>>3))*128 + (l16&7);
                offv[nt] = off;
                float s = sacc[mt][nt][r]*scale + bf2f(Ps[off]);
                if (shifted && grp[nt*16+l16] != myg) s -= 100.f;
                sv[nt] = s;
                mloc = fmaxf(mloc, s);
            }
            #pragma unroll
            for (int off=1; off<16; off<<=1) mloc = fmaxf(mloc, __shfl_xor(mloc, off));
            float lloc = 0.f;
            #pragma unroll
            for (int nt=0; nt<8; ++nt){
                float p = __expf(sv[nt]-mloc);
                sv[nt] = p; lloc += p;
            }
            #pragma unroll
            for (int off=1; off<16; off<<=1) lloc += __shfl_xor(lloc, off);
            #pragma unroll
            for (int nt=0; nt<8; ++nt)
                Ps[offv[nt]] = f2bf(sv[nt]);
            if (l16==0) linv[row] = 1.f/lloc;
        }
    }

    f32x4 oacc[2][2] = {};
    #pragma unroll
    for (int ks=0; ks<4; ++ks){
        bf16x8 av0 = *(const bf16x8*)&Vt[         ks*512 + quad*128 + l16*8];
        bf16x8 av1 = *(const bf16x8*)&Vt[ 2048 +  ks*512 + quad*128 + l16*8];
        bf16x8 pf0 = *(const bf16x8*)&Ps[(wave*2+0)*2048 + ks*512 + quad*128 + l16*8];
        bf16x8 pf1 = *(const bf16x8*)&Ps[(wave*2+1)*2048 + ks*512 + quad*128 + l16*8];
        oacc[0][0] = __builtin_amdgcn_mfma_f32_16x16x32_bf16(av0, pf0, oacc[0][0], 0,0,0);
        oacc[0][1] = __builtin_amdgcn_mfma_f32_16x16x32_bf16(av1, pf0, oacc[0][1], 0,0,0);
        oacc[1][0] = __builtin_amdgcn_mfma_f32_16x16x32_bf16(av0, pf1, oacc[1][0], 0,0,0);
        oacc[1][1] = __builtin_amdgcn_mfma_f32_16x16x32_bf16(av1, pf1, oacc[1][1], 0,0,0);
    }

    #pragma unroll
    for (int mt=0; mt<2; ++mt){
        int token = wave*32 + mt*16 + l16;
        float inv = linv[token];
        unsigned short* dst = obuf + (size_t)(wb*128+token)*CCH + head*32;
        #pragma unroll
        for (int dt=0; dt<2; ++dt){
            ushort4 v4;
            v4.x = f2bf(oacc[mt][dt][0]*inv);
            v4.y = f2bf(oacc[mt][dt][1]*inv);
            v4.z = f2bf(oacc[mt][dt][2]*inv);
            v4.w = f2bf(oacc[mt][dt][3]*inv);
            *(ushort4*)&dst[dt*16 + quad*4] = v4;
        }
    }
}

extern "C" void kernel_launch(void* const* d_in, const int* in_sizes, int n_in,
                              void* d_out, int out_size, void* d_ws, size_t ws_size,
                              hipStream_t stream) {
    const float* x       = (const float*)d_in[0];
    const float* pe_w    = (const float*)d_in[1];
    const float* pe_b    = (const float*)d_in[2];
    const float* pe_ln_g = (const float*)d_in[3];
    const float* pe_ln_b = (const float*)d_in[4];
    const float* ln1_g   = (const float*)d_in[5];
    const float* ln1_b   = (const float*)d_in[6];
    const float* qkv_w   = (const float*)d_in[7];
    const float* qkv_b   = (const float*)d_in[8];
    const float* proj_w  = (const float*)d_in[9];
    const float* proj_b  = (const float*)d_in[10];
    const float* rpb     = (const float*)d_in[11];
    const float* ln2_g   = (const float*)d_in[12];
    const float* ln2_b   = (const float*)d_in[13];
    const float* fc1_w   = (const float*)d_in[14];
    const float* fc1_b   = (const float*)d_in[15];
    const float* fc2_w   = (const float*)d_in[16];
    const float* fc2_b   = (const float*)d_in[17];
    const float* rec_w   = (const float*)d_in[18];
    const float* rec_b   = (const float*)d_in[19];
    float* out = (float*)d_out;
    char* wsb = (char*)d_ws;

    float*          e        = (float*)wsb;
    unsigned short* bias_il  = (unsigned short*)(wsb + 50331648);
    unsigned short* wt       = (unsigned short*)(wsb + 51904512);
    unsigned short* pwb      = wt + 1769472;
    unsigned short* rwt      = wt + 1794048;
    char*           stage    = wsb + 55541760;
    size_t scap = ws_size > 55541760 ? ws_size - 55541760 : 0;

    int WCH = 512;
    while (WCH > 16 && (size_t)WCH*128*1920 > scap) WCH >>= 1;

    for (int d = 0; d < 4; ++d){
        unsigned short* wl = wt + (size_t)d*442368;
        wt_convert<<<(110592+255)/256, 256, 0, stream>>>(qkv_w  + (size_t)d*110592, wl,          192, 576);
        wt_convert<<<( 36864+255)/256, 256, 0, stream>>>(proj_w + (size_t)d* 36864, wl + 110592, 192, 192);
        wt_convert<<<(147456+255)/256, 256, 0, stream>>>(fc1_w  + (size_t)d*147456, wl + 147456, 192, 768);
        wt_convert<<<(147456+255)/256, 256, 0, stream>>>(fc2_w  + (size_t)d*147456, wl + 294912, 768, 192);
    }
    pe_conv<<<96, 256, 0, stream>>>(pe_w, pwb, 24576);
    wt_convert<<<96, 256, 0, stream>>>(rec_w, rwt, 192, 128);

    bias_precompute<<<24, 128, 0, stream>>>(rpb, bias_il);
    patch_embed_mfma<<<1024, 256, 0, stream>>>(x, pwb, pe_b, pe_ln_g, pe_ln_b, e);

    for (int d = 0; d < 4; ++d){
        int sh = d & 1;
        unsigned short* wl = wt + (size_t)d*442368;
        for (int w0 = 0; w0 < 512; w0 += WCH){
            int rows = WCH*128;
            unsigned short* bufc = (unsigned short*)stage;
            unsigned short* qkc  = (unsigned short*)(stage + (size_t)rows*384);
            unsigned short* vc   = (unsigned short*)(stage + (size_t)rows*1152);
            unsigned short* oc   = (unsigned short*)(stage + (size_t)rows*1536);
            ln_kernel<<<rows, 192, 0, stream>>>(
                e, bufc, ln1_g + d*CCH, ln1_b + d*CCH, sh, w0*128);
            gemm_mfma<5><<<dim3(9, rows/128), 256, 0, stream>>>(
                bufc, wl, qkv_b + d*3*CCH, qkc, vc, 576, 192, 0, 0);
            attn_mfma<<<WCH*HEADS, 256, 0, stream>>>(
                qkc, vc, oc, bias_il + (size_t)d*HEADS*16384, sh, w0);
            gemm_mfma<2><<<dim3(3, rows/128), 256, 0, stream>>>(
                oc, wl + 110592, proj_b + d*CCH, e, nullptr, 192, 192, sh, w0*128);
        }
        mlp_fused<<<1024, 256, 0, stream>>>(
            e, wl + 147456, fc1_b + d*4*CCH, wl + 294912, fc2_b + d*CCH,
            ln2_g + d*CCH, ln2_b + d*CCH);
    }
    recon_mfma<<<1024, 256, 0, stream>>>(e, rwt, rec_b, out);
}